// Round 1
// baseline (1006.416 us; speedup 1.0000x reference)
//
#include <hip/hip_runtime.h>

typedef _Float16 half8 __attribute__((ext_vector_type(8)));
typedef float f32x4 __attribute__((ext_vector_type(4)));

// ---------------------------------------------------------------- transpose
// out[c][r] = in[r][c]; grid (cols/32, rows/32), 256 threads
__global__ __launch_bounds__(256) void transpose_f32(
    const float* __restrict__ in, int lda,
    float* __restrict__ out, int ldo)
{
  __shared__ float t[32][33];
  const int tx = threadIdx.x & 31, ty = threadIdx.x >> 5;
  const int bc = blockIdx.x * 32, br = blockIdx.y * 32;
#pragma unroll
  for (int i = 0; i < 4; ++i)
    t[ty + 8 * i][tx] = in[(size_t)(br + ty + 8 * i) * lda + bc + tx];
  __syncthreads();
#pragma unroll
  for (int i = 0; i < 4; ++i)
    out[(size_t)(bc + ty + 8 * i) * ldo + br + tx] = t[tx][ty + 8 * i];
}

// ---------------------------------------------------------------- GEMM (BT)
// C[m][n] = scale * sum_k A[m][k]*B[n][k] (+ bias[n]); A,B f32 row-major.
// f32 -> f16 hi/lo split during LDS staging; ASPL x BSPL passes (lo*lo skipped).
// 16x16x32 f16 MFMA; C-write mapping per m89/m90: row=(lane>>4)*4+j, col=lane&15.
template<int ASPL, int BSPL, int BM, int BN>
__global__ __launch_bounds__(256, 2) void gemm_bt(
    const float* __restrict__ Ag, int lda,
    const float* __restrict__ Bg, int ldb,
    float* __restrict__ Cg, int ldc,
    const float* __restrict__ bias,
    int K, float scale)
{
  constexpr int BK = 32;
  constexpr int WM = BM / 2, WN = BN / 2;
  constexpr int FM = WM / 16, FN = WN / 16;
  constexpr int NCA = (BM * 4) / 256;   // 8-f32 chunks per thread (A tile)
  constexpr int NCB = (BN * 4) / 256;
  static_assert((BM * 4) % 256 == 0 && (BN * 4) % 256 == 0, "tile/thread mismatch");

  __shared__ _Float16 ldsA[ASPL][BM][BK];
  __shared__ _Float16 ldsB[BSPL][BN][BK];

  const int tid  = threadIdx.x;
  const int lane = tid & 63;
  const int wid  = tid >> 6;
  const int wrow = wid >> 1, wcol = wid & 1;
  const int l15  = lane & 15, g = lane >> 4;

  const int brow = blockIdx.y * BM;
  const int bcol = blockIdx.x * BN;

  f32x4 acc[FM][FN];
#pragma unroll
  for (int mi = 0; mi < FM; ++mi)
#pragma unroll
    for (int ni = 0; ni < FN; ++ni)
      acc[mi][ni] = (f32x4){0.f, 0.f, 0.f, 0.f};

  float4 ra[NCA][2], rb[NCB][2];

  auto loadAB = [&](int kt) {
    const int k0 = kt * BK;
#pragma unroll
    for (int i = 0; i < NCA; ++i) {
      int c = tid + 256 * i;
      int row = c >> 2, ci = c & 3;
      const float4* p = (const float4*)(Ag + (size_t)(brow + row) * lda + k0 + ci * 8);
      ra[i][0] = p[0]; ra[i][1] = p[1];
    }
#pragma unroll
    for (int i = 0; i < NCB; ++i) {
      int c = tid + 256 * i;
      int row = c >> 2, ci = c & 3;
      const float4* p = (const float4*)(Bg + (size_t)(bcol + row) * ldb + k0 + ci * 8);
      rb[i][0] = p[0]; rb[i][1] = p[1];
    }
  };

  auto stageLDS = [&]() {
#pragma unroll
    for (int i = 0; i < NCA; ++i) {
      int c = tid + 256 * i;
      int row = c >> 2, ci = c & 3;
      float f[8] = {ra[i][0].x, ra[i][0].y, ra[i][0].z, ra[i][0].w,
                    ra[i][1].x, ra[i][1].y, ra[i][1].z, ra[i][1].w};
      half8 h, l;
#pragma unroll
      for (int j = 0; j < 8; ++j) {
        _Float16 hv = (_Float16)f[j];
        h[j] = hv;
        if (ASPL == 2) l[j] = (_Float16)(f[j] - (float)hv);
      }
      int off = row * BK + ((ci ^ ((row >> 1) & 3)) << 3);  // XOR swizzle
      *(half8*)(&ldsA[0][0][0] + off) = h;
      if (ASPL == 2) *(half8*)(&ldsA[1][0][0] + off) = l;
    }
#pragma unroll
    for (int i = 0; i < NCB; ++i) {
      int c = tid + 256 * i;
      int row = c >> 2, ci = c & 3;
      float f[8] = {rb[i][0].x, rb[i][0].y, rb[i][0].z, rb[i][0].w,
                    rb[i][1].x, rb[i][1].y, rb[i][1].z, rb[i][1].w};
      half8 h, l;
#pragma unroll
      for (int j = 0; j < 8; ++j) {
        _Float16 hv = (_Float16)f[j];
        h[j] = hv;
        if (BSPL == 2) l[j] = (_Float16)(f[j] - (float)hv);
      }
      int off = row * BK + ((ci ^ ((row >> 1) & 3)) << 3);
      *(half8*)(&ldsB[0][0][0] + off) = h;
      if (BSPL == 2) *(half8*)(&ldsB[1][0][0] + off) = l;
    }
  };

  const int nk = K / BK;
  loadAB(0);

  for (int kt = 0; kt < nk; ++kt) {
    stageLDS();
    if (kt + 1 < nk) loadAB(kt + 1);   // prefetch overlaps compute phase
    __syncthreads();

    half8 af[FM][ASPL];
#pragma unroll
    for (int mi = 0; mi < FM; ++mi)
#pragma unroll
      for (int sa = 0; sa < ASPL; ++sa) {
        int row = wrow * WM + mi * 16 + l15;
        af[mi][sa] = *(const half8*)(&ldsA[sa][0][0] + row * BK + ((g ^ ((row >> 1) & 3)) << 3));
      }
#pragma unroll
    for (int ni = 0; ni < FN; ++ni) {
      half8 bf[BSPL];
#pragma unroll
      for (int sb = 0; sb < BSPL; ++sb) {
        int row = wcol * WN + ni * 16 + l15;
        bf[sb] = *(const half8*)(&ldsB[sb][0][0] + row * BK + ((g ^ ((row >> 1) & 3)) << 3));
      }
#pragma unroll
      for (int mi = 0; mi < FM; ++mi)
#pragma unroll
        for (int sa = 0; sa < ASPL; ++sa)
#pragma unroll
          for (int sb = 0; sb < BSPL; ++sb) {
            if (ASPL == 2 && BSPL == 2 && sa == 1 && sb == 1) continue; // drop lo*lo
            acc[mi][ni] = __builtin_amdgcn_mfma_f32_16x16x32_f16(af[mi][sa], bf[sb], acc[mi][ni], 0, 0, 0);
          }
    }
    __syncthreads();
  }

#pragma unroll
  for (int mi = 0; mi < FM; ++mi)
#pragma unroll
    for (int ni = 0; ni < FN; ++ni) {
      int col = bcol + wcol * WN + ni * 16 + l15;
      float bv = bias ? bias[col] : 0.f;
#pragma unroll
      for (int j = 0; j < 4; ++j) {
        int r = brow + wrow * WM + mi * 16 + g * 4 + j;
        Cg[(size_t)r * ldc + col] = acc[mi][ni][j] * scale + bv;
      }
    }
}

// ---------------------------------------------------------------- softmax
// one block per row of 8192; row lives in 32 regs/thread; 1 read + 1 write
__global__ __launch_bounds__(256) void softmax_rows(float* __restrict__ attn)
{
  const int tid = threadIdx.x;
  float4* pv = (float4*)(attn + (size_t)blockIdx.x * 8192);
  float4 v[8];
#pragma unroll
  for (int i = 0; i < 8; ++i) v[i] = pv[i * 256 + tid];

  float m = -3.4e38f;
#pragma unroll
  for (int i = 0; i < 8; ++i)
    m = fmaxf(m, fmaxf(fmaxf(v[i].x, v[i].y), fmaxf(v[i].z, v[i].w)));
#pragma unroll
  for (int off = 32; off > 0; off >>= 1)
    m = fmaxf(m, __shfl_xor(m, off));
  __shared__ float red[4];
  if ((tid & 63) == 0) red[tid >> 6] = m;
  __syncthreads();
  m = fmaxf(fmaxf(red[0], red[1]), fmaxf(red[2], red[3]));

  float s = 0.f;
#pragma unroll
  for (int i = 0; i < 8; ++i) {
    v[i].x = __expf(v[i].x - m);
    v[i].y = __expf(v[i].y - m);
    v[i].z = __expf(v[i].z - m);
    v[i].w = __expf(v[i].w - m);
    s += (v[i].x + v[i].y) + (v[i].z + v[i].w);
  }
#pragma unroll
  for (int off = 32; off > 0; off >>= 1)
    s += __shfl_xor(s, off);
  __syncthreads();               // protect red[] reads above
  if ((tid & 63) == 0) red[tid >> 6] = s;
  __syncthreads();
  s = (red[0] + red[1]) + (red[2] + red[3]);
  float inv = 1.0f / s;
#pragma unroll
  for (int i = 0; i < 8; ++i) {
    v[i].x *= inv; v[i].y *= inv; v[i].z *= inv; v[i].w *= inv;
    pv[i * 256 + tid] = v[i];
  }
}

// ---------------------------------------------------------------- launch
extern "C" void kernel_launch(void* const* d_in, const int* in_sizes, int n_in,
                              void* d_out, int out_size, void* d_ws, size_t ws_size,
                              hipStream_t stream)
{
  const float* x    = (const float*)d_in[0];   // [8192,512]
  const float* Amat = (const float*)d_in[1];   // [8192,8192]
  const float* Wqkv = (const float*)d_in[2];   // [512,1536]
  const float* bqkv = (const float*)d_in[3];   // [1536]
  const float* Wo   = (const float*)d_in[4];   // [512,512]
  const float* bo   = (const float*)d_in[5];   // [512]

  float* o    = (float*)d_out;                       // [8192,512]
  float* attn = (float*)d_out + (size_t)8192 * 512;  // [8192,8192]

  float* ws    = (float*)d_ws;
  float* qkv   = ws;                                  // 8192*1536
  float* kbuf  = qkv   + (size_t)8192 * 1536;         // 8192*512
  float* k0T   = kbuf  + (size_t)8192 * 512;          // 512*8192
  float* vT    = k0T   + (size_t)512 * 8192;          // 512*8192
  float* WqkvT = vT    + (size_t)512 * 8192;          // 1536*512
  float* WoT   = WqkvT + (size_t)1536 * 512;          // 512*512
  float* vals  = WoT   + (size_t)512 * 512;           // 8192*512

  const dim3 b256(256);
  const float qk_scale = 0.04419417382415922f;  // 1/sqrt(512)

  // weight transposes (BT-form operands)
  transpose_f32<<<dim3(1536 / 32, 512 / 32), b256, 0, stream>>>(Wqkv, 1536, WqkvT, 512);
  transpose_f32<<<dim3(512 / 32, 512 / 32), b256, 0, stream>>>(Wo, 512, WoT, 512);

  // K1: qkv = x @ Wqkv + bqkv   (3-pass f16 split: ~fp32 accuracy)
  gemm_bt<2, 2, 128, 128><<<dim3(1536 / 128, 8192 / 128), b256, 0, stream>>>(
      x, 512, WqkvT, 512, qkv, 1536, bqkv, 512, 1.0f);

  // k0^T and v^T for BT-form GEMMs
  transpose_f32<<<dim3(512 / 32, 8192 / 32), b256, 0, stream>>>(qkv + 512, 1536, k0T, 8192);
  transpose_f32<<<dim3(512 / 32, 8192 / 32), b256, 0, stream>>>(qkv + 1024, 1536, vT, 8192);

  // K2: k = A @ k0   (A single f16, k0 split: 2-pass)
  gemm_bt<1, 2, 128, 64><<<dim3(512 / 64, 8192 / 128), b256, 0, stream>>>(
      Amat, 8192, k0T, 8192, kbuf, 512, nullptr, 8192, 1.0f);

  // K3: logits = (q @ k^T) * scale   (3-pass: q,k split)
  gemm_bt<2, 2, 128, 128><<<dim3(8192 / 128, 8192 / 128), b256, 0, stream>>>(
      qkv, 1536, kbuf, 512, attn, 8192, nullptr, 512, qk_scale);

  // K4: softmax rows (in place in d_out)
  softmax_rows<<<dim3(8192), b256, 0, stream>>>(attn);

  // K5: vals = attn @ v   (single-pass f16)
  gemm_bt<1, 1, 128, 64><<<dim3(512 / 64, 8192 / 128), b256, 0, stream>>>(
      attn, 8192, vT, 8192, vals, 512, nullptr, 8192, 1.0f);

  // K6: o = vals @ Wo + bo
  gemm_bt<1, 1, 128, 64><<<dim3(512 / 64, 8192 / 128), b256, 0, stream>>>(
      vals, 512, WoT, 512, o, 512, bo, 512, 1.0f);
}

// Round 2
// 764.618 us; speedup vs baseline: 1.3162x; 1.3162x over previous
//
#include <hip/hip_runtime.h>

typedef _Float16 half8 __attribute__((ext_vector_type(8)));
typedef float f32x4 __attribute__((ext_vector_type(4)));

// ---------------------------------------------------------------- transpose
__global__ __launch_bounds__(256) void transpose_f32(
    const float* __restrict__ in, int lda,
    float* __restrict__ out, int ldo)
{
  __shared__ float t[32][33];
  const int tx = threadIdx.x & 31, ty = threadIdx.x >> 5;
  const int bc = blockIdx.x * 32, br = blockIdx.y * 32;
#pragma unroll
  for (int i = 0; i < 4; ++i)
    t[ty + 8 * i][tx] = in[(size_t)(br + ty + 8 * i) * lda + bc + tx];
  __syncthreads();
#pragma unroll
  for (int i = 0; i < 4; ++i)
    out[(size_t)(bc + ty + 8 * i) * ldo + br + tx] = t[tx][ty + 8 * i];
}

// ---------------------------------------------------------------- GEMM (BT)
// C[m][n] = scale * sum_k A[m][k]*B[n][k] (+bias). f32->f16 hi/lo split staging.
// APART>1: A is APART planes (stride a_plane) summed during load (K6 fusion).
// STATS: epilogue emits per-(row, col-tile) max and sum-of-exp (K3 fusion).
// KSPLIT: blockIdx.z selects K-chunk; C offset by z*c_plane (K2 split-K).
template<int ASPL,int BSPL,int BM,int BN,int WAVES_M,int WAVES_N,int THREADS,
         int APART,bool STATS,bool KSPLIT,int MINW>
__global__ __launch_bounds__(THREADS, MINW) void gemm_bt(
    const float* __restrict__ Ag, int lda, size_t a_plane,
    const float* __restrict__ Bg, int ldb,
    float* __restrict__ Cg, int ldc, size_t c_plane,
    const float* __restrict__ bias, int K, float scale,
    float* __restrict__ mxout, float* __restrict__ smout, int ntiles)
{
  constexpr int BK = 32;
  constexpr int WM = BM / WAVES_M, WN = BN / WAVES_N;
  constexpr int FM = WM / 16, FN = WN / 16;
  constexpr int NCA = (BM * 4) / THREADS;
  constexpr int NCB = (BN * 4) / THREADS;
  static_assert((BM * 4) % THREADS == 0 && (BN * 4) % THREADS == 0, "mismatch");

  __shared__ _Float16 ldsA[ASPL][BM][BK];
  __shared__ _Float16 ldsB[BSPL][BN][BK];

  const int tid  = threadIdx.x;
  const int lane = tid & 63;
  const int wid  = tid >> 6;
  const int wrow = wid / WAVES_N, wcol = wid % WAVES_N;
  const int l15  = lane & 15, g = lane >> 4;
  const int brow = blockIdx.y * BM;
  const int bcol = blockIdx.x * BN;

  if constexpr (KSPLIT) {
    const int kc = blockIdx.z;
    Ag += (size_t)kc * K;        // column offset into A
    Bg += (size_t)kc * K;        // column offset into B
    Cg += (size_t)kc * c_plane;  // partial plane
  }

  f32x4 acc[FM][FN];
#pragma unroll
  for (int mi = 0; mi < FM; ++mi)
#pragma unroll
    for (int ni = 0; ni < FN; ++ni)
      acc[mi][ni] = (f32x4){0.f, 0.f, 0.f, 0.f};

  float4 ra[NCA][2], rb[NCB][2];

  auto loadAB = [&](int kt) {
    const int k0 = kt * BK;
#pragma unroll
    for (int i = 0; i < NCA; ++i) {
      int c = tid + THREADS * i;
      int row = c >> 2, ci = c & 3;
      const float* bp = Ag + (size_t)(brow + row) * lda + k0 + ci * 8;
      float4 u0 = ((const float4*)bp)[0];
      float4 u1 = ((const float4*)bp)[1];
#pragma unroll
      for (int p = 1; p < APART; ++p) {
        const float* pp = bp + (size_t)p * a_plane;
        float4 w0 = ((const float4*)pp)[0], w1 = ((const float4*)pp)[1];
        u0.x += w0.x; u0.y += w0.y; u0.z += w0.z; u0.w += w0.w;
        u1.x += w1.x; u1.y += w1.y; u1.z += w1.z; u1.w += w1.w;
      }
      ra[i][0] = u0; ra[i][1] = u1;
    }
#pragma unroll
    for (int i = 0; i < NCB; ++i) {
      int c = tid + THREADS * i;
      int row = c >> 2, ci = c & 3;
      const float4* p = (const float4*)(Bg + (size_t)(bcol + row) * ldb + k0 + ci * 8);
      rb[i][0] = p[0]; rb[i][1] = p[1];
    }
  };

  auto stageLDS = [&]() {
#pragma unroll
    for (int i = 0; i < NCA; ++i) {
      int c = tid + THREADS * i;
      int row = c >> 2, ci = c & 3;
      float f[8] = {ra[i][0].x, ra[i][0].y, ra[i][0].z, ra[i][0].w,
                    ra[i][1].x, ra[i][1].y, ra[i][1].z, ra[i][1].w};
      half8 h, l;
#pragma unroll
      for (int j = 0; j < 8; ++j) {
        _Float16 hv = (_Float16)f[j];
        h[j] = hv;
        if (ASPL == 2) l[j] = (_Float16)(f[j] - (float)hv);
      }
      int off = row * BK + ((ci ^ ((row >> 1) & 3)) << 3);
      *(half8*)(&ldsA[0][0][0] + off) = h;
      if (ASPL == 2) *(half8*)(&ldsA[1][0][0] + off) = l;
    }
#pragma unroll
    for (int i = 0; i < NCB; ++i) {
      int c = tid + THREADS * i;
      int row = c >> 2, ci = c & 3;
      float f[8] = {rb[i][0].x, rb[i][0].y, rb[i][0].z, rb[i][0].w,
                    rb[i][1].x, rb[i][1].y, rb[i][1].z, rb[i][1].w};
      half8 h, l;
#pragma unroll
      for (int j = 0; j < 8; ++j) {
        _Float16 hv = (_Float16)f[j];
        h[j] = hv;
        if (BSPL == 2) l[j] = (_Float16)(f[j] - (float)hv);
      }
      int off = row * BK + ((ci ^ ((row >> 1) & 3)) << 3);
      *(half8*)(&ldsB[0][0][0] + off) = h;
      if (BSPL == 2) *(half8*)(&ldsB[1][0][0] + off) = l;
    }
  };

  const int nk = K / BK;
  loadAB(0);

  for (int kt = 0; kt < nk; ++kt) {
    stageLDS();
    if (kt + 1 < nk) loadAB(kt + 1);
    __syncthreads();

    half8 af[FM][ASPL];
#pragma unroll
    for (int mi = 0; mi < FM; ++mi)
#pragma unroll
      for (int sa = 0; sa < ASPL; ++sa) {
        int row = wrow * WM + mi * 16 + l15;
        af[mi][sa] = *(const half8*)(&ldsA[sa][0][0] + row * BK + ((g ^ ((row >> 1) & 3)) << 3));
      }
#pragma unroll
    for (int ni = 0; ni < FN; ++ni) {
      half8 bf[BSPL];
#pragma unroll
      for (int sb = 0; sb < BSPL; ++sb) {
        int row = wcol * WN + ni * 16 + l15;
        bf[sb] = *(const half8*)(&ldsB[sb][0][0] + row * BK + ((g ^ ((row >> 1) & 3)) << 3));
      }
#pragma unroll
      for (int mi = 0; mi < FM; ++mi)
#pragma unroll
        for (int sa = 0; sa < ASPL; ++sa)
#pragma unroll
          for (int sb = 0; sb < BSPL; ++sb) {
            if (ASPL == 2 && BSPL == 2 && sa == 1 && sb == 1) continue;
            acc[mi][ni] = __builtin_amdgcn_mfma_f32_16x16x32_f16(af[mi][sa], bf[sb], acc[mi][ni], 0, 0, 0);
          }
    }
    __syncthreads();
  }

#pragma unroll
  for (int mi = 0; mi < FM; ++mi)
#pragma unroll
    for (int ni = 0; ni < FN; ++ni) {
      int col = bcol + wcol * WN + ni * 16 + l15;
      float bv = bias ? bias[col] : 0.f;
#pragma unroll
      for (int j = 0; j < 4; ++j) {
        int r = brow + wrow * WM + mi * 16 + g * 4 + j;
        Cg[(size_t)r * ldc + col] = acc[mi][ni][j] * scale + bv;
      }
    }

  if constexpr (STATS) {
    static_assert(WAVES_N == 2, "stats path assumes 2 column-waves");
    __shared__ float s_m2[BM][2];
    __shared__ float s_s2[BM][2];
#pragma unroll
    for (int mi = 0; mi < FM; ++mi)
#pragma unroll
      for (int j = 0; j < 4; ++j) {
        float v = -3.4e38f;
#pragma unroll
        for (int ni = 0; ni < FN; ++ni) v = fmaxf(v, acc[mi][ni][j] * scale);
        v = fmaxf(v, __shfl_xor(v, 1)); v = fmaxf(v, __shfl_xor(v, 2));
        v = fmaxf(v, __shfl_xor(v, 4)); v = fmaxf(v, __shfl_xor(v, 8));
        if (l15 == 0) s_m2[wrow * WM + mi * 16 + g * 4 + j][wcol] = v;
      }
    __syncthreads();
#pragma unroll
    for (int mi = 0; mi < FM; ++mi)
#pragma unroll
      for (int j = 0; j < 4; ++j) {
        int r = wrow * WM + mi * 16 + g * 4 + j;
        float mt = fmaxf(s_m2[r][0], s_m2[r][1]);
        float s = 0.f;
#pragma unroll
        for (int ni = 0; ni < FN; ++ni) s += __expf(acc[mi][ni][j] * scale - mt);
        s += __shfl_xor(s, 1); s += __shfl_xor(s, 2);
        s += __shfl_xor(s, 4); s += __shfl_xor(s, 8);
        if (l15 == 0) s_s2[r][wcol] = s;
      }
    __syncthreads();
    if (tid < BM) {
      float mt = fmaxf(s_m2[tid][0], s_m2[tid][1]);
      float st = s_s2[tid][0] + s_s2[tid][1];
      mxout[(size_t)(brow + tid) * ntiles + blockIdx.x] = mt;
      smout[(size_t)(brow + tid) * ntiles + blockIdx.x] = st;
    }
  }
}

// ---------------------------------------------------------------- reduce 4 planes
__global__ __launch_bounds__(256) void reduce4(
    const float4* __restrict__ in, float4* __restrict__ out, size_t plane4)
{
  size_t i = (size_t)blockIdx.x * 256 + threadIdx.x;
  float4 a = in[i], b = in[plane4 + i], c = in[2 * plane4 + i], d = in[3 * plane4 + i];
  out[i] = make_float4(a.x + b.x + c.x + d.x, a.y + b.y + c.y + d.y,
                       a.z + b.z + c.z + d.z, a.w + b.w + c.w + d.w);
}

// ---------------------------------------------------------------- stats combine
// one wave per row; lane = tile index (64 tiles)
__global__ __launch_bounds__(256) void softmax_combine(
    const float* __restrict__ mx, const float* __restrict__ sm,
    float* __restrict__ rowm, float* __restrict__ rowinv)
{
  const int row = blockIdx.x * 4 + (threadIdx.x >> 6);
  const int lane = threadIdx.x & 63;
  float mt = mx[(size_t)row * 64 + lane];
  float m = mt;
#pragma unroll
  for (int off = 32; off; off >>= 1) m = fmaxf(m, __shfl_xor(m, off));
  float s = sm[(size_t)row * 64 + lane] * __expf(mt - m);
#pragma unroll
  for (int off = 32; off; off >>= 1) s += __shfl_xor(s, off);
  if (lane == 0) { rowm[row] = m; rowinv[row] = 1.0f / s; }
}

// ---------------------------------------------------------------- fused attn-write + PV
// grid (4 kchunks, 64 rowblocks), 512 thr. Reads logits, writes attention
// in place, accumulates vals partials (scaled by 1/s during staging).
__global__ __launch_bounds__(512, 1) void pv_fused(
    float* __restrict__ attn,          // [8192][8192] logits in, attention out
    const float* __restrict__ vT,      // [512][8192]
    const float* __restrict__ rowm, const float* __restrict__ rowinv,
    float* __restrict__ vals_p)        // [4][8192][512]
{
  constexpr int BM = 128, BN = 512, BK = 32, NSTEP = 64;  // KC = 2048
  __shared__ _Float16 ldsA[BM][BK];
  __shared__ _Float16 ldsB[BN][BK];
  __shared__ float s_m[BM], s_inv[BM];

  const int tid = threadIdx.x, lane = tid & 63, wid = tid >> 6;
  const int wrow = wid >> 2, wcol = wid & 3;   // 2 x 4 waves
  const int l15 = lane & 15, g = lane >> 4;
  const int kc = blockIdx.x, brow = blockIdx.y * BM;
  const size_t kbase = (size_t)kc * 2048;

  if (tid < BM) { s_m[tid] = rowm[brow + tid]; s_inv[tid] = rowinv[brow + tid]; }

  f32x4 acc[4][8];
#pragma unroll
  for (int mi = 0; mi < 4; ++mi)
#pragma unroll
    for (int ni = 0; ni < 8; ++ni) acc[mi][ni] = (f32x4){0.f, 0.f, 0.f, 0.f};

  const int arow = tid >> 2, aci = tid & 3;
  float4 ra[2], rb[4][2];

  auto loadA = [&](int kt) {
    const float4* p = (const float4*)(attn + (size_t)(brow + arow) * 8192 + kbase + kt * BK + aci * 8);
    ra[0] = p[0]; ra[1] = p[1];
  };
  auto loadB = [&](int kt) {
#pragma unroll
    for (int i = 0; i < 4; ++i) {
      int c = tid + 512 * i; int r = c >> 2, ci = c & 3;
      const float4* p = (const float4*)(vT + (size_t)r * 8192 + kbase + kt * BK + ci * 8);
      rb[i][0] = p[0]; rb[i][1] = p[1];
    }
  };
  auto stage = [&](int kt) {
    const float m = s_m[arow], inv = s_inv[arow];
    float f[8] = {ra[0].x, ra[0].y, ra[0].z, ra[0].w, ra[1].x, ra[1].y, ra[1].z, ra[1].w};
    float e[8]; half8 h;
#pragma unroll
    for (int j = 0; j < 8; ++j) {
      e[j] = __expf(f[j] - m) * inv;
      h[j] = (_Float16)e[j];
    }
    float4* w = (float4*)(attn + (size_t)(brow + arow) * 8192 + kbase + kt * BK + aci * 8);
    w[0] = make_float4(e[0], e[1], e[2], e[3]);
    w[1] = make_float4(e[4], e[5], e[6], e[7]);
    int off = arow * BK + ((aci ^ ((arow >> 1) & 3)) << 3);
    *(half8*)(&ldsA[0][0] + off) = h;
#pragma unroll
    for (int i = 0; i < 4; ++i) {
      int c = tid + 512 * i; int r = c >> 2, ci = c & 3;
      float fb[8] = {rb[i][0].x, rb[i][0].y, rb[i][0].z, rb[i][0].w,
                     rb[i][1].x, rb[i][1].y, rb[i][1].z, rb[i][1].w};
      half8 hb;
#pragma unroll
      for (int j = 0; j < 8; ++j) hb[j] = (_Float16)fb[j];
      int off2 = r * BK + ((ci ^ ((r >> 1) & 3)) << 3);
      *(half8*)(&ldsB[0][0] + off2) = hb;
    }
  };

  loadA(0); loadB(0);
  __syncthreads();  // s_m/s_inv ready

  for (int kt = 0; kt < NSTEP; ++kt) {
    stage(kt);
    if (kt + 1 < NSTEP) { loadA(kt + 1); loadB(kt + 1); }
    __syncthreads();
    half8 af[4];
#pragma unroll
    for (int mi = 0; mi < 4; ++mi) {
      int row = wrow * 64 + mi * 16 + l15;
      af[mi] = *(const half8*)(&ldsA[0][0] + row * BK + ((g ^ ((row >> 1) & 3)) << 3));
    }
#pragma unroll
    for (int ni = 0; ni < 8; ++ni) {
      int rn = wcol * 128 + ni * 16 + l15;
      half8 bf = *(const half8*)(&ldsB[0][0] + rn * BK + ((g ^ ((rn >> 1) & 3)) << 3));
#pragma unroll
      for (int mi = 0; mi < 4; ++mi)
        acc[mi][ni] = __builtin_amdgcn_mfma_f32_16x16x32_f16(af[mi], bf, acc[mi][ni], 0, 0, 0);
    }
    __syncthreads();
  }

  const size_t plane = (size_t)8192 * 512;
#pragma unroll
  for (int mi = 0; mi < 4; ++mi)
#pragma unroll
    for (int ni = 0; ni < 8; ++ni) {
      int col = wcol * 128 + ni * 16 + l15;
#pragma unroll
      for (int j = 0; j < 4; ++j) {
        int row = brow + wrow * 64 + mi * 16 + g * 4 + j;
        vals_p[(size_t)kc * plane + (size_t)row * 512 + col] = acc[mi][ni][j];
      }
    }
}

// ---------------------------------------------------------------- launch
extern "C" void kernel_launch(void* const* d_in, const int* in_sizes, int n_in,
                              void* d_out, int out_size, void* d_ws, size_t ws_size,
                              hipStream_t stream)
{
  const float* x    = (const float*)d_in[0];
  const float* Amat = (const float*)d_in[1];
  const float* Wqkv = (const float*)d_in[2];
  const float* bqkv = (const float*)d_in[3];
  const float* Wo   = (const float*)d_in[4];
  const float* bo   = (const float*)d_in[5];

  float* o    = (float*)d_out;                       // [8192,512]
  float* attn = (float*)d_out + (size_t)8192 * 512;  // [8192,8192]

  float* ws     = (float*)d_ws;
  float* qkv    = ws;                                // 12,582,912
  float* k0T    = ws + 12582912;                     //  4,194,304
  float* vals_p = ws;                                // 16,777,216 (reuses qkv+k0T)
  float* vT     = ws + 16777216;                     //  4,194,304
  float* WqkvT  = ws + 20971520;                     //    786,432
  float* WoT    = ws + 21757952;                     //    262,144
  float* kbuf   = ws + 22020096;                     //  4,194,304
  float* mx     = ws + 26214400;                     //    524,288
  float* sm     = ws + 26738688;                     //    524,288
  float* rowm   = ws + 27262976;                     //      8,192
  float* rowinv = ws + 27271168;                     //      8,192
  float* kpart  = attn;                              // d_out attn region as scratch pre-K3

  const dim3 b256(256), b512(512);
  const float qk_scale = 0.04419417382415922f;  // 1/sqrt(512)
  const size_t plane = (size_t)8192 * 512;

  transpose_f32<<<dim3(48, 16), b256, 0, stream>>>(Wqkv, 1536, WqkvT, 512);
  transpose_f32<<<dim3(16, 16), b256, 0, stream>>>(Wo, 512, WoT, 512);

  // K1: qkv = x @ Wqkv + bqkv   (3-pass)
  gemm_bt<2, 2, 128, 128, 2, 2, 256, 1, false, false, 2>
      <<<dim3(12, 64), b256, 0, stream>>>(
      x, 512, 0, WqkvT, 512, qkv, 1536, 0, bqkv, 512, 1.0f, nullptr, nullptr, 0);

  transpose_f32<<<dim3(16, 256), b256, 0, stream>>>(qkv + 512, 1536, k0T, 8192);
  transpose_f32<<<dim3(16, 256), b256, 0, stream>>>(qkv + 1024, 1536, vT, 8192);

  // K2: k = A @ k0, split-K into 4 chunks, partials in d_out scratch
  gemm_bt<1, 2, 128, 256, 2, 4, 512, 1, false, true, 1>
      <<<dim3(2, 64, 4), b512, 0, stream>>>(
      Amat, 8192, 0, k0T, 8192, kpart, 512, plane, nullptr, 2048, 1.0f, nullptr, nullptr, 0);

  reduce4<<<dim3(4096), b256, 0, stream>>>((const float4*)kpart, (float4*)kbuf, plane / 4);

  // K3: logits = (q @ k^T)*scale  (2-pass: k split)  + per-tile softmax stats
  gemm_bt<1, 2, 128, 128, 2, 2, 256, 1, true, false, 2>
      <<<dim3(64, 64), b256, 0, stream>>>(
      qkv, 1536, 0, kbuf, 512, attn, 8192, 0, nullptr, 512, qk_scale, mx, sm, 64);

  softmax_combine<<<dim3(2048), b256, 0, stream>>>(mx, sm, rowm, rowinv);

  // K5': attention = exp(l-m)/s written in place; vals partials accumulated
  pv_fused<<<dim3(4, 64), b512, 0, stream>>>(attn, vT, rowm, rowinv, vals_p);

  // K6: o = (sum of 4 vals partials) @ Wo + bo
  gemm_bt<1, 1, 128, 128, 2, 2, 256, 4, false, false, 2>
      <<<dim3(4, 64), b256, 0, stream>>>(
      vals_p, 512, plane, WoT, 512, o, 512, 0, bo, 512, 1.0f, nullptr, nullptr, 0);
}

// Round 3
// 732.602 us; speedup vs baseline: 1.3738x; 1.0437x over previous
//
#include <hip/hip_runtime.h>

typedef _Float16 half8 __attribute__((ext_vector_type(8)));
typedef float f32x4 __attribute__((ext_vector_type(4)));

// ---------------------------------------------------------------- transpose
__global__ __launch_bounds__(256) void transpose_f32(
    const float* __restrict__ in, int lda,
    float* __restrict__ out, int ldo)
{
  __shared__ float t[32][33];
  const int tx = threadIdx.x & 31, ty = threadIdx.x >> 5;
  const int bc = blockIdx.x * 32, br = blockIdx.y * 32;
#pragma unroll
  for (int i = 0; i < 4; ++i)
    t[ty + 8 * i][tx] = in[(size_t)(br + ty + 8 * i) * lda + bc + tx];
  __syncthreads();
#pragma unroll
  for (int i = 0; i < 4; ++i)
    out[(size_t)(bc + ty + 8 * i) * ldo + br + tx] = t[tx][ty + 8 * i];
}

// transpose with f32 -> f16 convert on output
__global__ __launch_bounds__(256) void transpose_f32_f16(
    const float* __restrict__ in, int lda,
    _Float16* __restrict__ out, int ldo)
{
  __shared__ float t[32][33];
  const int tx = threadIdx.x & 31, ty = threadIdx.x >> 5;
  const int bc = blockIdx.x * 32, br = blockIdx.y * 32;
#pragma unroll
  for (int i = 0; i < 4; ++i)
    t[ty + 8 * i][tx] = in[(size_t)(br + ty + 8 * i) * lda + bc + tx];
  __syncthreads();
#pragma unroll
  for (int i = 0; i < 4; ++i)
    out[(size_t)(bc + ty + 8 * i) * ldo + br + tx] = (_Float16)t[tx][ty + 8 * i];
}

// ---------------------------------------------------------------- GEMM (BT)
// C[m][n] = scale * sum_k A[m][k]*B[n][k] (+bias). f32->f16 hi/lo split staging.
// APART>1: A is APART planes (stride a_plane) summed during load (K6 fusion).
// STATS: epilogue emits per-(row, col-tile) max and sum-of-exp (K3 fusion).
// KSPLIT: blockIdx.z selects K-chunk; C offset by z*c_plane (K2 split-K).
template<int ASPL,int BSPL,int BM,int BN,int WAVES_M,int WAVES_N,int THREADS,
         int APART,bool STATS,bool KSPLIT,int MINW>
__global__ __launch_bounds__(THREADS, MINW) void gemm_bt(
    const float* __restrict__ Ag, int lda, size_t a_plane,
    const float* __restrict__ Bg, int ldb,
    float* __restrict__ Cg, int ldc, size_t c_plane,
    const float* __restrict__ bias, int K, float scale,
    float* __restrict__ mxout, float* __restrict__ smout, int ntiles)
{
  constexpr int BK = 32;
  constexpr int WM = BM / WAVES_M, WN = BN / WAVES_N;
  constexpr int FM = WM / 16, FN = WN / 16;
  constexpr int NCA = (BM * 4) / THREADS;
  constexpr int NCB = (BN * 4) / THREADS;
  static_assert((BM * 4) % THREADS == 0 && (BN * 4) % THREADS == 0, "mismatch");

  __shared__ _Float16 ldsA[ASPL][BM][BK];
  __shared__ _Float16 ldsB[BSPL][BN][BK];

  const int tid  = threadIdx.x;
  const int lane = tid & 63;
  const int wid  = tid >> 6;
  const int wrow = wid / WAVES_N, wcol = wid % WAVES_N;
  const int l15  = lane & 15, g = lane >> 4;
  const int brow = blockIdx.y * BM;
  const int bcol = blockIdx.x * BN;

  if constexpr (KSPLIT) {
    const int kc = blockIdx.z;
    Ag += (size_t)kc * K;        // column offset into A
    Bg += (size_t)kc * K;        // column offset into B
    Cg += (size_t)kc * c_plane;  // partial plane
  }

  f32x4 acc[FM][FN];
#pragma unroll
  for (int mi = 0; mi < FM; ++mi)
#pragma unroll
    for (int ni = 0; ni < FN; ++ni)
      acc[mi][ni] = (f32x4){0.f, 0.f, 0.f, 0.f};

  float4 ra[NCA][2], rb[NCB][2];

  auto loadAB = [&](int kt) {
    const int k0 = kt * BK;
#pragma unroll
    for (int i = 0; i < NCA; ++i) {
      int c = tid + THREADS * i;
      int row = c >> 2, ci = c & 3;
      const float* bp = Ag + (size_t)(brow + row) * lda + k0 + ci * 8;
      float4 u0 = ((const float4*)bp)[0];
      float4 u1 = ((const float4*)bp)[1];
#pragma unroll
      for (int p = 1; p < APART; ++p) {
        const float* pp = bp + (size_t)p * a_plane;
        float4 w0 = ((const float4*)pp)[0], w1 = ((const float4*)pp)[1];
        u0.x += w0.x; u0.y += w0.y; u0.z += w0.z; u0.w += w0.w;
        u1.x += w1.x; u1.y += w1.y; u1.z += w1.z; u1.w += w1.w;
      }
      ra[i][0] = u0; ra[i][1] = u1;
    }
#pragma unroll
    for (int i = 0; i < NCB; ++i) {
      int c = tid + THREADS * i;
      int row = c >> 2, ci = c & 3;
      const float4* p = (const float4*)(Bg + (size_t)(bcol + row) * ldb + k0 + ci * 8);
      rb[i][0] = p[0]; rb[i][1] = p[1];
    }
  };

  auto stageLDS = [&]() {
#pragma unroll
    for (int i = 0; i < NCA; ++i) {
      int c = tid + THREADS * i;
      int row = c >> 2, ci = c & 3;
      float f[8] = {ra[i][0].x, ra[i][0].y, ra[i][0].z, ra[i][0].w,
                    ra[i][1].x, ra[i][1].y, ra[i][1].z, ra[i][1].w};
      half8 h, l;
#pragma unroll
      for (int j = 0; j < 8; ++j) {
        _Float16 hv = (_Float16)f[j];
        h[j] = hv;
        if (ASPL == 2) l[j] = (_Float16)(f[j] - (float)hv);
      }
      int off = row * BK + ((ci ^ ((row >> 1) & 3)) << 3);
      *(half8*)(&ldsA[0][0][0] + off) = h;
      if (ASPL == 2) *(half8*)(&ldsA[1][0][0] + off) = l;
    }
#pragma unroll
    for (int i = 0; i < NCB; ++i) {
      int c = tid + THREADS * i;
      int row = c >> 2, ci = c & 3;
      float f[8] = {rb[i][0].x, rb[i][0].y, rb[i][0].z, rb[i][0].w,
                    rb[i][1].x, rb[i][1].y, rb[i][1].z, rb[i][1].w};
      half8 h, l;
#pragma unroll
      for (int j = 0; j < 8; ++j) {
        _Float16 hv = (_Float16)f[j];
        h[j] = hv;
        if (BSPL == 2) l[j] = (_Float16)(f[j] - (float)hv);
      }
      int off = row * BK + ((ci ^ ((row >> 1) & 3)) << 3);
      *(half8*)(&ldsB[0][0][0] + off) = h;
      if (BSPL == 2) *(half8*)(&ldsB[1][0][0] + off) = l;
    }
  };

  const int nk = K / BK;
  loadAB(0);

  for (int kt = 0; kt < nk; ++kt) {
    stageLDS();
    if (kt + 1 < nk) loadAB(kt + 1);
    __syncthreads();

    half8 af[FM][ASPL];
#pragma unroll
    for (int mi = 0; mi < FM; ++mi)
#pragma unroll
      for (int sa = 0; sa < ASPL; ++sa) {
        int row = wrow * WM + mi * 16 + l15;
        af[mi][sa] = *(const half8*)(&ldsA[sa][0][0] + row * BK + ((g ^ ((row >> 1) & 3)) << 3));
      }
#pragma unroll
    for (int ni = 0; ni < FN; ++ni) {
      half8 bf[BSPL];
#pragma unroll
      for (int sb = 0; sb < BSPL; ++sb) {
        int row = wcol * WN + ni * 16 + l15;
        bf[sb] = *(const half8*)(&ldsB[sb][0][0] + row * BK + ((g ^ ((row >> 1) & 3)) << 3));
      }
#pragma unroll
      for (int mi = 0; mi < FM; ++mi)
#pragma unroll
        for (int sa = 0; sa < ASPL; ++sa)
#pragma unroll
          for (int sb = 0; sb < BSPL; ++sb) {
            if (ASPL == 2 && BSPL == 2 && sa == 1 && sb == 1) continue;
            acc[mi][ni] = __builtin_amdgcn_mfma_f32_16x16x32_f16(af[mi][sa], bf[sb], acc[mi][ni], 0, 0, 0);
          }
    }
    __syncthreads();
  }

#pragma unroll
  for (int mi = 0; mi < FM; ++mi)
#pragma unroll
    for (int ni = 0; ni < FN; ++ni) {
      int col = bcol + wcol * WN + ni * 16 + l15;
      float bv = bias ? bias[col] : 0.f;
#pragma unroll
      for (int j = 0; j < 4; ++j) {
        int r = brow + wrow * WM + mi * 16 + g * 4 + j;
        Cg[(size_t)r * ldc + col] = acc[mi][ni][j] * scale + bv;
      }
    }

  if constexpr (STATS) {
    static_assert(WAVES_N == 2, "stats path assumes 2 column-waves");
    __shared__ float s_m2[BM][2];
    __shared__ float s_s2[BM][2];
#pragma unroll
    for (int mi = 0; mi < FM; ++mi)
#pragma unroll
      for (int j = 0; j < 4; ++j) {
        float v = -3.4e38f;
#pragma unroll
        for (int ni = 0; ni < FN; ++ni) v = fmaxf(v, acc[mi][ni][j] * scale);
        v = fmaxf(v, __shfl_xor(v, 1)); v = fmaxf(v, __shfl_xor(v, 2));
        v = fmaxf(v, __shfl_xor(v, 4)); v = fmaxf(v, __shfl_xor(v, 8));
        if (l15 == 0) s_m2[wrow * WM + mi * 16 + g * 4 + j][wcol] = v;
      }
    __syncthreads();
#pragma unroll
    for (int mi = 0; mi < FM; ++mi)
#pragma unroll
      for (int j = 0; j < 4; ++j) {
        int r = wrow * WM + mi * 16 + g * 4 + j;
        float mt = fmaxf(s_m2[r][0], s_m2[r][1]);
        float s = 0.f;
#pragma unroll
        for (int ni = 0; ni < FN; ++ni) s += __expf(acc[mi][ni][j] * scale - mt);
        s += __shfl_xor(s, 1); s += __shfl_xor(s, 2);
        s += __shfl_xor(s, 4); s += __shfl_xor(s, 8);
        if (l15 == 0) s_s2[r][wcol] = s;
      }
    __syncthreads();
    if (tid < BM) {
      float mt = fmaxf(s_m2[tid][0], s_m2[tid][1]);
      float st = s_s2[tid][0] + s_s2[tid][1];
      mxout[(size_t)(brow + tid) * ntiles + blockIdx.x] = mt;
      smout[(size_t)(brow + tid) * ntiles + blockIdx.x] = st;
    }
  }
}

// ---------------------------------------------------------------- reduce 4 planes
__global__ __launch_bounds__(256) void reduce4(
    const float4* __restrict__ in, float4* __restrict__ out, size_t plane4)
{
  size_t i = (size_t)blockIdx.x * 256 + threadIdx.x;
  float4 a = in[i], b = in[plane4 + i], c = in[2 * plane4 + i], d = in[3 * plane4 + i];
  out[i] = make_float4(a.x + b.x + c.x + d.x, a.y + b.y + c.y + d.y,
                       a.z + b.z + c.z + d.z, a.w + b.w + c.w + d.w);
}

// ---------------------------------------------------------------- stats combine
__global__ __launch_bounds__(256) void softmax_combine(
    const float* __restrict__ mx, const float* __restrict__ sm,
    float* __restrict__ rowm, float* __restrict__ rowinv)
{
  const int row = blockIdx.x * 4 + (threadIdx.x >> 6);
  const int lane = threadIdx.x & 63;
  float mt = mx[(size_t)row * 64 + lane];
  float m = mt;
#pragma unroll
  for (int off = 32; off; off >>= 1) m = fmaxf(m, __shfl_xor(m, off));
  float s = sm[(size_t)row * 64 + lane] * __expf(mt - m);
#pragma unroll
  for (int off = 32; off; off >>= 1) s += __shfl_xor(s, off);
  if (lane == 0) { rowm[row] = m; rowinv[row] = 1.0f / s; }
}

// ---------------------------------------------------------------- fused attn-write + PV
// grid (4 kchunks, 128 rowblocks) = 512 blocks, 512 thr, 2 blocks/CU.
// Double-buffered LDS, ONE barrier per K-step. V pre-converted to f16.
__global__ __launch_bounds__(512, 4) void pv_fused(
    float* __restrict__ attn,            // [8192][8192] logits in, attention out
    const _Float16* __restrict__ vT16,   // [512][8192] f16
    const float* __restrict__ rowm, const float* __restrict__ rowinv,
    float* __restrict__ vals_p)          // [4][8192][512]
{
  constexpr int BM = 64, BN = 512, BK = 32, NSTEP = 64;  // KC = 2048
  __shared__ _Float16 ldsA[2][BM][BK];   // 8 KB
  __shared__ _Float16 ldsB[2][BN][BK];   // 64 KB
  __shared__ float s_m[BM], s_inv[BM];

  const int tid = threadIdx.x, lane = tid & 63, wid = tid >> 6;
  const int wrow = wid >> 2, wcol = wid & 3;   // 2 x 4 waves
  const int l15 = lane & 15, g = lane >> 4;
  const int kc = blockIdx.x, brow = blockIdx.y * BM;
  const size_t kbase = (size_t)kc * 2048;

  if (tid < BM) { s_m[tid] = rowm[brow + tid]; s_inv[tid] = rowinv[brow + tid]; }

  f32x4 acc[2][8];
#pragma unroll
  for (int mi = 0; mi < 2; ++mi)
#pragma unroll
    for (int ni = 0; ni < 8; ++ni) acc[mi][ni] = (f32x4){0.f, 0.f, 0.f, 0.f};

  // A handled by threads 0..255 (waves 0-3): 64 rows x 32 k, 8 f32 each
  const int arow = (tid & 255) >> 2, aci = tid & 3;
  float4 ra[2];
  half8 rbh[4];

  auto loadA = [&](int kt) {
    if (tid < 256) {
      const float4* p = (const float4*)(attn + (size_t)(brow + arow) * 8192 + kbase + kt * BK + aci * 8);
      ra[0] = p[0]; ra[1] = p[1];
    }
  };
  auto loadB = [&](int kt) {
#pragma unroll
    for (int i = 0; i < 4; ++i) {
      int c = tid + 512 * i; int r = c >> 2, ci = c & 3;
      rbh[i] = *(const half8*)(vT16 + (size_t)r * 8192 + kbase + kt * BK + ci * 8);
    }
  };
  auto stage = [&](int kt, int b) {
    if (tid < 256) {
      const float m = s_m[arow], inv = s_inv[arow];
      float f[8] = {ra[0].x, ra[0].y, ra[0].z, ra[0].w, ra[1].x, ra[1].y, ra[1].z, ra[1].w};
      float e[8]; half8 h;
#pragma unroll
      for (int j = 0; j < 8; ++j) {
        e[j] = __expf(f[j] - m) * inv;
        h[j] = (_Float16)e[j];
      }
      float4* w = (float4*)(attn + (size_t)(brow + arow) * 8192 + kbase + kt * BK + aci * 8);
      w[0] = make_float4(e[0], e[1], e[2], e[3]);
      w[1] = make_float4(e[4], e[5], e[6], e[7]);
      int off = arow * BK + ((aci ^ ((arow >> 1) & 3)) << 3);
      *(half8*)(&ldsA[b][0][0] + off) = h;
    }
#pragma unroll
    for (int i = 0; i < 4; ++i) {
      int c = tid + 512 * i; int r = c >> 2, ci = c & 3;
      int off2 = r * BK + ((ci ^ ((r >> 1) & 3)) << 3);
      *(half8*)(&ldsB[b][0][0] + off2) = rbh[i];
    }
  };

  loadA(0); loadB(0);
  __syncthreads();            // s_m / s_inv visible
  stage(0, 0);
  loadA(1); loadB(1);
  __syncthreads();            // buf0 staged

  for (int kt = 0; kt < NSTEP; ++kt) {
    const int cur = kt & 1, nxt = cur ^ 1;
    if (kt + 1 < NSTEP) stage(kt + 1, nxt);         // fill other buffer
    if (kt + 2 < NSTEP) { loadA(kt + 2); loadB(kt + 2); }  // prefetch
    half8 af[2];
#pragma unroll
    for (int mi = 0; mi < 2; ++mi) {
      int row = wrow * 32 + mi * 16 + l15;
      af[mi] = *(const half8*)(&ldsA[cur][0][0] + row * BK + ((g ^ ((row >> 1) & 3)) << 3));
    }
#pragma unroll
    for (int ni = 0; ni < 8; ++ni) {
      int rn = wcol * 128 + ni * 16 + l15;
      half8 bf = *(const half8*)(&ldsB[cur][0][0] + rn * BK + ((g ^ ((rn >> 1) & 3)) << 3));
#pragma unroll
      for (int mi = 0; mi < 2; ++mi)
        acc[mi][ni] = __builtin_amdgcn_mfma_f32_16x16x32_f16(af[mi], bf, acc[mi][ni], 0, 0, 0);
    }
    __syncthreads();          // single barrier per K-step
  }

  const size_t plane = (size_t)8192 * 512;
#pragma unroll
  for (int mi = 0; mi < 2; ++mi)
#pragma unroll
    for (int ni = 0; ni < 8; ++ni) {
      int col = wcol * 128 + ni * 16 + l15;
#pragma unroll
      for (int j = 0; j < 4; ++j) {
        int row = brow + wrow * 32 + mi * 16 + g * 4 + j;
        vals_p[(size_t)kc * plane + (size_t)row * 512 + col] = acc[mi][ni][j];
      }
    }
}

// ---------------------------------------------------------------- launch
extern "C" void kernel_launch(void* const* d_in, const int* in_sizes, int n_in,
                              void* d_out, int out_size, void* d_ws, size_t ws_size,
                              hipStream_t stream)
{
  const float* x    = (const float*)d_in[0];
  const float* Amat = (const float*)d_in[1];
  const float* Wqkv = (const float*)d_in[2];
  const float* bqkv = (const float*)d_in[3];
  const float* Wo   = (const float*)d_in[4];
  const float* bo   = (const float*)d_in[5];

  float* o    = (float*)d_out;                       // [8192,512]
  float* attn = (float*)d_out + (size_t)8192 * 512;  // [8192,8192]

  float* ws = (float*)d_ws;
  // Lifetimes: qkv/k0T dead before pv_fused writes vals_p (same region).
  float*     vals_p = ws;                         // 16,777,216 floats (4 planes)
  float*     qkv    = ws;                         // 12,582,912 (dead after K3)
  float*     k0T    = ws + 12582912;              //  4,194,304 (dead after K2)
  _Float16*  vT16   = (_Float16*)(ws + 16777216); //  2,097,152 float-slots
  float*     WqkvT  = ws + 18874368;              //    786,432
  float*     WoT    = ws + 19660800;              //    262,144
  float*     kbuf   = ws + 19922944;              //  4,194,304
  float*     mx     = ws + 24117248;              //    524,288
  float*     sm     = ws + 24641536;              //    524,288
  float*     rowm   = ws + 25165824;              //      8,192
  float*     rowinv = ws + 25174016;              //      8,192
  float*     kpart  = attn;                       // d_out attn region pre-K3

  const dim3 b256(256), b512(512);
  const float qk_scale = 0.04419417382415922f;  // 1/sqrt(512)
  const size_t plane = (size_t)8192 * 512;

  transpose_f32<<<dim3(48, 16), b256, 0, stream>>>(Wqkv, 1536, WqkvT, 512);
  transpose_f32<<<dim3(16, 16), b256, 0, stream>>>(Wo, 512, WoT, 512);

  // K1: qkv = x @ Wqkv + bqkv   (3-pass)
  gemm_bt<2, 2, 128, 128, 2, 2, 256, 1, false, false, 2>
      <<<dim3(12, 64), b256, 0, stream>>>(
      x, 512, 0, WqkvT, 512, qkv, 1536, 0, bqkv, 512, 1.0f, nullptr, nullptr, 0);

  transpose_f32<<<dim3(16, 256), b256, 0, stream>>>(qkv + 512, 1536, k0T, 8192);
  transpose_f32_f16<<<dim3(16, 256), b256, 0, stream>>>(qkv + 1024, 1536, vT16, 8192);

  // K2: k = A @ k0, split-K into 4 chunks, partials in d_out scratch
  gemm_bt<1, 2, 128, 256, 2, 4, 512, 1, false, true, 1>
      <<<dim3(2, 64, 4), b512, 0, stream>>>(
      Amat, 8192, 0, k0T, 8192, kpart, 512, plane, nullptr, 2048, 1.0f, nullptr, nullptr, 0);

  reduce4<<<dim3(4096), b256, 0, stream>>>((const float4*)kpart, (float4*)kbuf, plane / 4);

  // K3: logits = (q @ k^T)*scale  (2-pass: k split)  + per-tile softmax stats
  gemm_bt<1, 2, 128, 128, 2, 2, 256, 1, true, false, 2>
      <<<dim3(64, 64), b256, 0, stream>>>(
      qkv, 1536, 0, kbuf, 512, attn, 8192, 0, nullptr, 512, qk_scale, mx, sm, 64);

  softmax_combine<<<dim3(2048), b256, 0, stream>>>(mx, sm, rowm, rowinv);

  // K5': attention = exp(l-m)/s in place; vals partials (dbuf, 512 blocks)
  pv_fused<<<dim3(4, 128), b512, 0, stream>>>(attn, vT16, rowm, rowinv, vals_p);

  // K6: o = (sum of 4 vals partials) @ Wo + bo
  gemm_bt<1, 1, 128, 128, 2, 2, 256, 4, false, false, 2>
      <<<dim3(4, 64), b256, 0, stream>>>(
      vals_p, 512, plane, WoT, 512, o, 512, 0, bo, 512, 1.0f, nullptr, nullptr, 0);
}

// Round 4
// 715.455 us; speedup vs baseline: 1.4067x; 1.0240x over previous
//
#include <hip/hip_runtime.h>

typedef _Float16 half8 __attribute__((ext_vector_type(8)));
typedef float f32x4 __attribute__((ext_vector_type(4)));

// ---------------------------------------------------------------- transpose
__global__ __launch_bounds__(256) void transpose_f32(
    const float* __restrict__ in, int lda,
    float* __restrict__ out, int ldo)
{
  __shared__ float t[32][33];
  const int tx = threadIdx.x & 31, ty = threadIdx.x >> 5;
  const int bc = blockIdx.x * 32, br = blockIdx.y * 32;
#pragma unroll
  for (int i = 0; i < 4; ++i)
    t[ty + 8 * i][tx] = in[(size_t)(br + ty + 8 * i) * lda + bc + tx];
  __syncthreads();
#pragma unroll
  for (int i = 0; i < 4; ++i)
    out[(size_t)(bc + ty + 8 * i) * ldo + br + tx] = t[tx][ty + 8 * i];
}

// transpose with f32 -> f16 convert on output
__global__ __launch_bounds__(256) void transpose_f32_f16(
    const float* __restrict__ in, int lda,
    _Float16* __restrict__ out, int ldo)
{
  __shared__ float t[32][33];
  const int tx = threadIdx.x & 31, ty = threadIdx.x >> 5;
  const int bc = blockIdx.x * 32, br = blockIdx.y * 32;
#pragma unroll
  for (int i = 0; i < 4; ++i)
    t[ty + 8 * i][tx] = in[(size_t)(br + ty + 8 * i) * lda + bc + tx];
  __syncthreads();
#pragma unroll
  for (int i = 0; i < 4; ++i)
    out[(size_t)(bc + ty + 8 * i) * ldo + br + tx] = (_Float16)t[tx][ty + 8 * i];
}

// ---------------------------------------------------------------- half column-sum
// csum[d] = 0.5 * sum_l k0T[d][l]   (k0T is [512][8192])
__global__ __launch_bounds__(256) void halfcolsum(
    const float* __restrict__ k0T, float* __restrict__ csum)
{
  const int d = blockIdx.x, tid = threadIdx.x;
  const float4* p = (const float4*)(k0T + (size_t)d * 8192);
  float s = 0.f;
#pragma unroll
  for (int i = 0; i < 8; ++i) {
    float4 v = p[i * 256 + tid];
    s += (v.x + v.y) + (v.z + v.w);
  }
#pragma unroll
  for (int off = 32; off; off >>= 1) s += __shfl_xor(s, off);
  __shared__ float r[4];
  if ((tid & 63) == 0) r[tid >> 6] = s;
  __syncthreads();
  if (tid == 0) csum[d] = 0.5f * ((r[0] + r[1]) + (r[2] + r[3]));
}

// ---------------------------------------------------------------- GEMM (BT)
// C[m][n] = scale * sum_k A[m][k]*B[n][k] (+bias). f32->f16 hi/lo split staging.
// Double-buffered LDS, ONE barrier per K-step.
// APART>1: A is APART planes (stride a_plane) summed during load (K6 fusion).
// STATS: epilogue emits per-(row, col-tile) max and sum-of-exp (K3 fusion).
// KSPLIT: blockIdx.z selects K-chunk; C offset by z*c_plane (K2 split-K).
template<int ASPL,int BSPL,int BM,int BN,int WAVES_M,int WAVES_N,int THREADS,
         int APART,bool STATS,bool KSPLIT,int MINW>
__global__ __launch_bounds__(THREADS, MINW) void gemm_bt(
    const float* __restrict__ Ag, int lda, size_t a_plane,
    const float* __restrict__ Bg, int ldb,
    float* __restrict__ Cg, int ldc, size_t c_plane,
    const float* __restrict__ bias, int K, float scale,
    float* __restrict__ mxout, float* __restrict__ smout, int ntiles)
{
  constexpr int BK = 32;
  constexpr int WM = BM / WAVES_M, WN = BN / WAVES_N;
  constexpr int FM = WM / 16, FN = WN / 16;
  constexpr int NCA = (BM * 4) / THREADS;
  constexpr int NCB = (BN * 4) / THREADS;
  static_assert((BM * 4) % THREADS == 0 && (BN * 4) % THREADS == 0, "mismatch");

  __shared__ _Float16 ldsA[2][ASPL][BM][BK];
  __shared__ _Float16 ldsB[2][BSPL][BN][BK];

  const int tid  = threadIdx.x;
  const int lane = tid & 63;
  const int wid  = tid >> 6;
  const int wrow = wid / WAVES_N, wcol = wid % WAVES_N;
  const int l15  = lane & 15, g = lane >> 4;
  const int brow = blockIdx.y * BM;
  const int bcol = blockIdx.x * BN;

  if constexpr (KSPLIT) {
    const int kc = blockIdx.z;
    Ag += (size_t)kc * K;
    Bg += (size_t)kc * K;
    Cg += (size_t)kc * c_plane;
  }

  f32x4 acc[FM][FN];
#pragma unroll
  for (int mi = 0; mi < FM; ++mi)
#pragma unroll
    for (int ni = 0; ni < FN; ++ni)
      acc[mi][ni] = (f32x4){0.f, 0.f, 0.f, 0.f};

  float4 ra[NCA][2], rb[NCB][2];

  auto loadAB = [&](int kt) {
    const int k0 = kt * BK;
#pragma unroll
    for (int i = 0; i < NCA; ++i) {
      int c = tid + THREADS * i;
      int row = c >> 2, ci = c & 3;
      const float* bp = Ag + (size_t)(brow + row) * lda + k0 + ci * 8;
      float4 u0 = ((const float4*)bp)[0];
      float4 u1 = ((const float4*)bp)[1];
#pragma unroll
      for (int p = 1; p < APART; ++p) {
        const float* pp = bp + (size_t)p * a_plane;
        float4 w0 = ((const float4*)pp)[0], w1 = ((const float4*)pp)[1];
        u0.x += w0.x; u0.y += w0.y; u0.z += w0.z; u0.w += w0.w;
        u1.x += w1.x; u1.y += w1.y; u1.z += w1.z; u1.w += w1.w;
      }
      ra[i][0] = u0; ra[i][1] = u1;
    }
#pragma unroll
    for (int i = 0; i < NCB; ++i) {
      int c = tid + THREADS * i;
      int row = c >> 2, ci = c & 3;
      const float4* p = (const float4*)(Bg + (size_t)(bcol + row) * ldb + k0 + ci * 8);
      rb[i][0] = p[0]; rb[i][1] = p[1];
    }
  };

  auto stageLDS = [&](int b) {
#pragma unroll
    for (int i = 0; i < NCA; ++i) {
      int c = tid + THREADS * i;
      int row = c >> 2, ci = c & 3;
      float f[8] = {ra[i][0].x, ra[i][0].y, ra[i][0].z, ra[i][0].w,
                    ra[i][1].x, ra[i][1].y, ra[i][1].z, ra[i][1].w};
      half8 h, l;
#pragma unroll
      for (int j = 0; j < 8; ++j) {
        _Float16 hv = (_Float16)f[j];
        h[j] = hv;
        if (ASPL == 2) l[j] = (_Float16)(f[j] - (float)hv);
      }
      int off = row * BK + ((ci ^ ((row >> 1) & 3)) << 3);
      *(half8*)(&ldsA[b][0][0][0] + off) = h;
      if (ASPL == 2) *(half8*)(&ldsA[b][1][0][0] + off) = l;
    }
#pragma unroll
    for (int i = 0; i < NCB; ++i) {
      int c = tid + THREADS * i;
      int row = c >> 2, ci = c & 3;
      float f[8] = {rb[i][0].x, rb[i][0].y, rb[i][0].z, rb[i][0].w,
                    rb[i][1].x, rb[i][1].y, rb[i][1].z, rb[i][1].w};
      half8 h, l;
#pragma unroll
      for (int j = 0; j < 8; ++j) {
        _Float16 hv = (_Float16)f[j];
        h[j] = hv;
        if (BSPL == 2) l[j] = (_Float16)(f[j] - (float)hv);
      }
      int off = row * BK + ((ci ^ ((row >> 1) & 3)) << 3);
      *(half8*)(&ldsB[b][0][0][0] + off) = h;
      if (BSPL == 2) *(half8*)(&ldsB[b][1][0][0] + off) = l;
    }
  };

  const int nk = K / BK;
  loadAB(0);
  stageLDS(0);
  if (nk > 1) loadAB(1);
  __syncthreads();

  for (int kt = 0; kt < nk; ++kt) {
    const int cur = kt & 1, nxt = cur ^ 1;
    if (kt + 1 < nk) stageLDS(nxt);          // fill other buffer (regs from loadAB(kt+1))
    if (kt + 2 < nk) loadAB(kt + 2);         // prefetch

    half8 af[FM][ASPL];
#pragma unroll
    for (int mi = 0; mi < FM; ++mi)
#pragma unroll
      for (int sa = 0; sa < ASPL; ++sa) {
        int row = wrow * WM + mi * 16 + l15;
        af[mi][sa] = *(const half8*)(&ldsA[cur][sa][0][0] + row * BK + ((g ^ ((row >> 1) & 3)) << 3));
      }
#pragma unroll
    for (int ni = 0; ni < FN; ++ni) {
      half8 bf[BSPL];
#pragma unroll
      for (int sb = 0; sb < BSPL; ++sb) {
        int row = wcol * WN + ni * 16 + l15;
        bf[sb] = *(const half8*)(&ldsB[cur][sb][0][0] + row * BK + ((g ^ ((row >> 1) & 3)) << 3));
      }
#pragma unroll
      for (int mi = 0; mi < FM; ++mi)
#pragma unroll
        for (int sa = 0; sa < ASPL; ++sa)
#pragma unroll
          for (int sb = 0; sb < BSPL; ++sb) {
            if (ASPL == 2 && BSPL == 2 && sa == 1 && sb == 1) continue;
            acc[mi][ni] = __builtin_amdgcn_mfma_f32_16x16x32_f16(af[mi][sa], bf[sb], acc[mi][ni], 0, 0, 0);
          }
    }
    __syncthreads();                         // single barrier per K-step
  }

#pragma unroll
  for (int mi = 0; mi < FM; ++mi)
#pragma unroll
    for (int ni = 0; ni < FN; ++ni) {
      int col = bcol + wcol * WN + ni * 16 + l15;
      float bv = bias ? bias[col] : 0.f;
#pragma unroll
      for (int j = 0; j < 4; ++j) {
        int r = brow + wrow * WM + mi * 16 + g * 4 + j;
        Cg[(size_t)r * ldc + col] = acc[mi][ni][j] * scale + bv;
      }
    }

  if constexpr (STATS) {
    static_assert(WAVES_N == 2, "stats path assumes 2 column-waves");
    __shared__ float s_m2[BM][2];
    __shared__ float s_s2[BM][2];
#pragma unroll
    for (int mi = 0; mi < FM; ++mi)
#pragma unroll
      for (int j = 0; j < 4; ++j) {
        float v = -3.4e38f;
#pragma unroll
        for (int ni = 0; ni < FN; ++ni) v = fmaxf(v, acc[mi][ni][j] * scale);
        v = fmaxf(v, __shfl_xor(v, 1)); v = fmaxf(v, __shfl_xor(v, 2));
        v = fmaxf(v, __shfl_xor(v, 4)); v = fmaxf(v, __shfl_xor(v, 8));
        if (l15 == 0) s_m2[wrow * WM + mi * 16 + g * 4 + j][wcol] = v;
      }
    __syncthreads();
#pragma unroll
    for (int mi = 0; mi < FM; ++mi)
#pragma unroll
      for (int j = 0; j < 4; ++j) {
        int r = wrow * WM + mi * 16 + g * 4 + j;
        float mt = fmaxf(s_m2[r][0], s_m2[r][1]);
        float s = 0.f;
#pragma unroll
        for (int ni = 0; ni < FN; ++ni) s += __expf(acc[mi][ni][j] * scale - mt);
        s += __shfl_xor(s, 1); s += __shfl_xor(s, 2);
        s += __shfl_xor(s, 4); s += __shfl_xor(s, 8);
        if (l15 == 0) s_s2[r][wcol] = s;
      }
    __syncthreads();
    if (tid < BM) {
      float mt = fmaxf(s_m2[tid][0], s_m2[tid][1]);
      float st = s_s2[tid][0] + s_s2[tid][1];
      mxout[(size_t)(brow + tid) * ntiles + blockIdx.x] = mt;
      smout[(size_t)(brow + tid) * ntiles + blockIdx.x] = st;
    }
  }
}

// ---------------------------------------------------------------- reduce 4 planes (+ mean-shift subtract)
// out = sum of 4 partials - csum4[d]  (softmax is invariant to this per-row shift)
__global__ __launch_bounds__(256) void reduce4(
    const float4* __restrict__ in, float4* __restrict__ out, size_t plane4,
    const float4* __restrict__ csum4)
{
  size_t i = (size_t)blockIdx.x * 256 + threadIdx.x;
  float4 a = in[i], b = in[plane4 + i], c = in[2 * plane4 + i], d = in[3 * plane4 + i];
  float4 s = csum4[i & 127];   // row length 512 f32 = 128 float4
  out[i] = make_float4(a.x + b.x + c.x + d.x - s.x, a.y + b.y + c.y + d.y - s.y,
                       a.z + b.z + c.z + d.z - s.z, a.w + b.w + c.w + d.w - s.w);
}

// ---------------------------------------------------------------- stats combine
__global__ __launch_bounds__(256) void softmax_combine(
    const float* __restrict__ mx, const float* __restrict__ sm,
    float* __restrict__ rowm, float* __restrict__ rowinv)
{
  const int row = blockIdx.x * 4 + (threadIdx.x >> 6);
  const int lane = threadIdx.x & 63;
  float mt = mx[(size_t)row * 64 + lane];
  float m = mt;
#pragma unroll
  for (int off = 32; off; off >>= 1) m = fmaxf(m, __shfl_xor(m, off));
  float s = sm[(size_t)row * 64 + lane] * __expf(mt - m);
#pragma unroll
  for (int off = 32; off; off >>= 1) s += __shfl_xor(s, off);
  if (lane == 0) { rowm[row] = m; rowinv[row] = 1.0f / s; }
}

// ---------------------------------------------------------------- fused attn-write + PV
__global__ __launch_bounds__(512, 4) void pv_fused(
    float* __restrict__ attn,            // [8192][8192] logits in, attention out
    const _Float16* __restrict__ vT16,   // [512][8192] f16
    const float* __restrict__ rowm, const float* __restrict__ rowinv,
    float* __restrict__ vals_p)          // [4][8192][512]
{
  constexpr int BM = 64, BN = 512, BK = 32, NSTEP = 64;  // KC = 2048
  __shared__ _Float16 ldsA[2][BM][BK];   // 8 KB
  __shared__ _Float16 ldsB[2][BN][BK];   // 64 KB
  __shared__ float s_m[BM], s_inv[BM];

  const int tid = threadIdx.x, lane = tid & 63, wid = tid >> 6;
  const int wrow = wid >> 2, wcol = wid & 3;   // 2 x 4 waves
  const int l15 = lane & 15, g = lane >> 4;
  const int kc = blockIdx.x, brow = blockIdx.y * BM;
  const size_t kbase = (size_t)kc * 2048;

  if (tid < BM) { s_m[tid] = rowm[brow + tid]; s_inv[tid] = rowinv[brow + tid]; }

  f32x4 acc[2][8];
#pragma unroll
  for (int mi = 0; mi < 2; ++mi)
#pragma unroll
    for (int ni = 0; ni < 8; ++ni) acc[mi][ni] = (f32x4){0.f, 0.f, 0.f, 0.f};

  const int arow = (tid & 255) >> 2, aci = tid & 3;
  float4 ra[2];
  half8 rbh[4];

  auto loadA = [&](int kt) {
    if (tid < 256) {
      const float4* p = (const float4*)(attn + (size_t)(brow + arow) * 8192 + kbase + kt * BK + aci * 8);
      ra[0] = p[0]; ra[1] = p[1];
    }
  };
  auto loadB = [&](int kt) {
#pragma unroll
    for (int i = 0; i < 4; ++i) {
      int c = tid + 512 * i; int r = c >> 2, ci = c & 3;
      rbh[i] = *(const half8*)(vT16 + (size_t)r * 8192 + kbase + kt * BK + ci * 8);
    }
  };
  auto stage = [&](int kt, int b) {
    if (tid < 256) {
      const float m = s_m[arow], inv = s_inv[arow];
      float f[8] = {ra[0].x, ra[0].y, ra[0].z, ra[0].w, ra[1].x, ra[1].y, ra[1].z, ra[1].w};
      float e[8]; half8 h;
#pragma unroll
      for (int j = 0; j < 8; ++j) {
        e[j] = __expf(f[j] - m) * inv;
        h[j] = (_Float16)e[j];
      }
      float4* w = (float4*)(attn + (size_t)(brow + arow) * 8192 + kbase + kt * BK + aci * 8);
      w[0] = make_float4(e[0], e[1], e[2], e[3]);
      w[1] = make_float4(e[4], e[5], e[6], e[7]);
      int off = arow * BK + ((aci ^ ((arow >> 1) & 3)) << 3);
      *(half8*)(&ldsA[b][0][0] + off) = h;
    }
#pragma unroll
    for (int i = 0; i < 4; ++i) {
      int c = tid + 512 * i; int r = c >> 2, ci = c & 3;
      int off2 = r * BK + ((ci ^ ((r >> 1) & 3)) << 3);
      *(half8*)(&ldsB[b][0][0] + off2) = rbh[i];
    }
  };

  loadA(0); loadB(0);
  __syncthreads();            // s_m / s_inv visible
  stage(0, 0);
  loadA(1); loadB(1);
  __syncthreads();            // buf0 staged

  for (int kt = 0; kt < NSTEP; ++kt) {
    const int cur = kt & 1, nxt = cur ^ 1;
    if (kt + 1 < NSTEP) stage(kt + 1, nxt);
    if (kt + 2 < NSTEP) { loadA(kt + 2); loadB(kt + 2); }
    half8 af[2];
#pragma unroll
    for (int mi = 0; mi < 2; ++mi) {
      int row = wrow * 32 + mi * 16 + l15;
      af[mi] = *(const half8*)(&ldsA[cur][0][0] + row * BK + ((g ^ ((row >> 1) & 3)) << 3));
    }
#pragma unroll
    for (int ni = 0; ni < 8; ++ni) {
      int rn = wcol * 128 + ni * 16 + l15;
      half8 bf = *(const half8*)(&ldsB[cur][0][0] + rn * BK + ((g ^ ((rn >> 1) & 3)) << 3));
#pragma unroll
      for (int mi = 0; mi < 2; ++mi)
        acc[mi][ni] = __builtin_amdgcn_mfma_f32_16x16x32_f16(af[mi], bf, acc[mi][ni], 0, 0, 0);
    }
    __syncthreads();
  }

  const size_t plane = (size_t)8192 * 512;
#pragma unroll
  for (int mi = 0; mi < 2; ++mi)
#pragma unroll
    for (int ni = 0; ni < 8; ++ni) {
      int col = wcol * 128 + ni * 16 + l15;
#pragma unroll
      for (int j = 0; j < 4; ++j) {
        int row = brow + wrow * 32 + mi * 16 + g * 4 + j;
        vals_p[(size_t)kc * plane + (size_t)row * 512 + col] = acc[mi][ni][j];
      }
    }
}

// ---------------------------------------------------------------- launch
extern "C" void kernel_launch(void* const* d_in, const int* in_sizes, int n_in,
                              void* d_out, int out_size, void* d_ws, size_t ws_size,
                              hipStream_t stream)
{
  const float* x    = (const float*)d_in[0];
  const float* Amat = (const float*)d_in[1];
  const float* Wqkv = (const float*)d_in[2];
  const float* bqkv = (const float*)d_in[3];
  const float* Wo   = (const float*)d_in[4];
  const float* bo   = (const float*)d_in[5];

  float* o    = (float*)d_out;                       // [8192,512]
  float* attn = (float*)d_out + (size_t)8192 * 512;  // [8192,8192]

  float* ws = (float*)d_ws;
  float*     vals_p = ws;                         // 16,777,216 floats (4 planes)
  float*     qkv    = ws;                         // 12,582,912 (dead after K3)
  float*     k0T    = ws + 12582912;              //  4,194,304 (dead after K2/halfcolsum)
  _Float16*  vT16   = (_Float16*)(ws + 16777216); //  2,097,152 float-slots
  float*     WqkvT  = ws + 18874368;              //    786,432
  float*     WoT    = ws + 19660800;              //    262,144
  float*     kbuf   = ws + 19922944;              //  4,194,304
  float*     mx     = ws + 24117248;              //    524,288
  float*     sm     = ws + 24641536;              //    524,288
  float*     rowm   = ws + 25165824;              //      8,192
  float*     rowinv = ws + 25174016;              //      8,192
  float*     csum   = ws + 25182208;              //        512
  float*     kpart  = attn;                       // d_out attn region pre-K3

  const dim3 b256(256), b512(512);
  const float qk_scale = 0.04419417382415922f;  // 1/sqrt(512)
  const size_t plane = (size_t)8192 * 512;

  transpose_f32<<<dim3(48, 16), b256, 0, stream>>>(Wqkv, 1536, WqkvT, 512);
  transpose_f32<<<dim3(16, 16), b256, 0, stream>>>(Wo, 512, WoT, 512);

  // K1: qkv = x @ Wqkv + bqkv   (3-pass)
  gemm_bt<2, 2, 128, 128, 2, 2, 256, 1, false, false, 2>
      <<<dim3(12, 64), b256, 0, stream>>>(
      x, 512, 0, WqkvT, 512, qkv, 1536, 0, bqkv, 512, 1.0f, nullptr, nullptr, 0);

  transpose_f32<<<dim3(16, 256), b256, 0, stream>>>(qkv + 512, 1536, k0T, 8192);
  transpose_f32_f16<<<dim3(16, 256), b256, 0, stream>>>(qkv + 1024, 1536, vT16, 8192);
  halfcolsum<<<dim3(512), b256, 0, stream>>>(k0T, csum);

  // K2: k = A @ k0, split-K into 4 chunks, partials in d_out scratch
  gemm_bt<1, 2, 128, 256, 2, 4, 512, 1, false, true, 4>
      <<<dim3(2, 64, 4), b512, 0, stream>>>(
      Amat, 8192, 0, k0T, 8192, kpart, 512, plane, nullptr, 2048, 1.0f, nullptr, nullptr, 0);

  // kbuf = sum of partials - 0.5*colsum(k0)  (softmax-invariant shift, shrinks |k| ~2x)
  reduce4<<<dim3(4096), b256, 0, stream>>>((const float4*)kpart, (float4*)kbuf, plane / 4,
                                           (const float4*)csum);

  // K3: logits = (q @ k^T)*scale  (1-pass, mean-removed k)  + per-tile softmax stats
  gemm_bt<1, 1, 128, 128, 2, 2, 256, 1, true, false, 3>
      <<<dim3(64, 64), b256, 0, stream>>>(
      qkv, 1536, 0, kbuf, 512, attn, 8192, 0, nullptr, 512, qk_scale, mx, sm, 64);

  softmax_combine<<<dim3(2048), b256, 0, stream>>>(mx, sm, rowm, rowinv);

  // K5': attention = exp(l-m)/s in place; vals partials (dbuf, 512 blocks)
  pv_fused<<<dim3(4, 128), b512, 0, stream>>>(attn, vT16, rowm, rowinv, vals_p);

  // K6: o = (sum of 4 vals partials) @ Wo + bo
  gemm_bt<1, 1, 128, 128, 2, 2, 256, 4, false, false, 3>
      <<<dim3(4, 64), b256, 0, stream>>>(
      vals_p, 512, plane, WoT, 512, o, 512, 0, bo, 512, 1.0f, nullptr, nullptr, 0);
}

// Round 5
// 652.142 us; speedup vs baseline: 1.5432x; 1.0971x over previous
//
#include <hip/hip_runtime.h>

typedef _Float16 half8 __attribute__((ext_vector_type(8)));
typedef _Float16 half4 __attribute__((ext_vector_type(4)));
typedef float f32x4 __attribute__((ext_vector_type(4)));

// ---------------------------------------------------------------- transpose
__global__ __launch_bounds__(256) void transpose_f32(
    const float* __restrict__ in, int lda,
    float* __restrict__ out, int ldo)
{
  __shared__ float t[32][33];
  const int tx = threadIdx.x & 31, ty = threadIdx.x >> 5;
  const int bc = blockIdx.x * 32, br = blockIdx.y * 32;
#pragma unroll
  for (int i = 0; i < 4; ++i)
    t[ty + 8 * i][tx] = in[(size_t)(br + ty + 8 * i) * lda + bc + tx];
  __syncthreads();
#pragma unroll
  for (int i = 0; i < 4; ++i)
    out[(size_t)(bc + ty + 8 * i) * ldo + br + tx] = t[tx][ty + 8 * i];
}

// transpose with f32 -> f16 convert on output
__global__ __launch_bounds__(256) void transpose_f32_f16(
    const float* __restrict__ in, int lda,
    _Float16* __restrict__ out, int ldo)
{
  __shared__ float t[32][33];
  const int tx = threadIdx.x & 31, ty = threadIdx.x >> 5;
  const int bc = blockIdx.x * 32, br = blockIdx.y * 32;
#pragma unroll
  for (int i = 0; i < 4; ++i)
    t[ty + 8 * i][tx] = in[(size_t)(br + ty + 8 * i) * lda + bc + tx];
  __syncthreads();
#pragma unroll
  for (int i = 0; i < 4; ++i)
    out[(size_t)(bc + ty + 8 * i) * ldo + br + tx] = (_Float16)t[tx][ty + 8 * i];
}

// ---------------------------------------------------------------- half column-sum
// csum[d] = 0.5 * sum_l k0T[d][l]   (k0T is [512][8192])
__global__ __launch_bounds__(256) void halfcolsum(
    const float* __restrict__ k0T, float* __restrict__ csum)
{
  const int d = blockIdx.x, tid = threadIdx.x;
  const float4* p = (const float4*)(k0T + (size_t)d * 8192);
  float s = 0.f;
#pragma unroll
  for (int i = 0; i < 8; ++i) {
    float4 v = p[i * 256 + tid];
    s += (v.x + v.y) + (v.z + v.w);
  }
#pragma unroll
  for (int off = 32; off; off >>= 1) s += __shfl_xor(s, off);
  __shared__ float r[4];
  if ((tid & 63) == 0) r[tid >> 6] = s;
  __syncthreads();
  if (tid == 0) csum[d] = 0.5f * ((r[0] + r[1]) + (r[2] + r[3]));
}

// ---------------------------------------------------------------- GEMM (BT), f32 in
// C[m][n] = scale * sum_k A[m][k]*B[n][k] (+bias). f32->f16 hi/lo split staging.
// Double-buffered LDS, ONE barrier per K-step.
// APART>1: A is APART planes (stride a_plane) summed during load (K6 fusion).
// KSPLIT: blockIdx.z selects K-chunk; C offset by z*c_plane (K2 split-K).
// QF16: extra f16 store of C (cols<512) to q16out (K1 fusion).
template<int ASPL,int BSPL,int BM,int BN,int WAVES_M,int WAVES_N,int THREADS,
         int APART,bool KSPLIT,bool QF16,int MINW>
__global__ __launch_bounds__(THREADS, MINW) void gemm_bt(
    const float* __restrict__ Ag, int lda, size_t a_plane,
    const float* __restrict__ Bg, int ldb,
    float* __restrict__ Cg, int ldc, size_t c_plane,
    const float* __restrict__ bias, int K, float scale,
    _Float16* __restrict__ q16out)
{
  constexpr int BK = 32;
  constexpr int WM = BM / WAVES_M, WN = BN / WAVES_N;
  constexpr int FM = WM / 16, FN = WN / 16;
  constexpr int NCA = (BM * 4) / THREADS;
  constexpr int NCB = (BN * 4) / THREADS;
  static_assert((BM * 4) % THREADS == 0 && (BN * 4) % THREADS == 0, "mismatch");

  __shared__ _Float16 ldsA[2][ASPL][BM][BK];
  __shared__ _Float16 ldsB[2][BSPL][BN][BK];

  const int tid  = threadIdx.x;
  const int lane = tid & 63;
  const int wid  = tid >> 6;
  const int wrow = wid / WAVES_N, wcol = wid % WAVES_N;
  const int l15  = lane & 15, g = lane >> 4;
  const int brow = blockIdx.y * BM;
  const int bcol = blockIdx.x * BN;

  if constexpr (KSPLIT) {
    const int kc = blockIdx.z;
    Ag += (size_t)kc * K;
    Bg += (size_t)kc * K;
    Cg += (size_t)kc * c_plane;
  }

  f32x4 acc[FM][FN];
#pragma unroll
  for (int mi = 0; mi < FM; ++mi)
#pragma unroll
    for (int ni = 0; ni < FN; ++ni)
      acc[mi][ni] = (f32x4){0.f, 0.f, 0.f, 0.f};

  float4 ra[NCA][2], rb[NCB][2];

  auto loadAB = [&](int kt) {
    const int k0 = kt * BK;
#pragma unroll
    for (int i = 0; i < NCA; ++i) {
      int c = tid + THREADS * i;
      int row = c >> 2, ci = c & 3;
      const float* bp = Ag + (size_t)(brow + row) * lda + k0 + ci * 8;
      float4 u0 = ((const float4*)bp)[0];
      float4 u1 = ((const float4*)bp)[1];
#pragma unroll
      for (int p = 1; p < APART; ++p) {
        const float* pp = bp + (size_t)p * a_plane;
        float4 w0 = ((const float4*)pp)[0], w1 = ((const float4*)pp)[1];
        u0.x += w0.x; u0.y += w0.y; u0.z += w0.z; u0.w += w0.w;
        u1.x += w1.x; u1.y += w1.y; u1.z += w1.z; u1.w += w1.w;
      }
      ra[i][0] = u0; ra[i][1] = u1;
    }
#pragma unroll
    for (int i = 0; i < NCB; ++i) {
      int c = tid + THREADS * i;
      int row = c >> 2, ci = c & 3;
      const float4* p = (const float4*)(Bg + (size_t)(bcol + row) * ldb + k0 + ci * 8);
      rb[i][0] = p[0]; rb[i][1] = p[1];
    }
  };

  auto stageLDS = [&](int b) {
#pragma unroll
    for (int i = 0; i < NCA; ++i) {
      int c = tid + THREADS * i;
      int row = c >> 2, ci = c & 3;
      float f[8] = {ra[i][0].x, ra[i][0].y, ra[i][0].z, ra[i][0].w,
                    ra[i][1].x, ra[i][1].y, ra[i][1].z, ra[i][1].w};
      half8 h, l;
#pragma unroll
      for (int j = 0; j < 8; ++j) {
        _Float16 hv = (_Float16)f[j];
        h[j] = hv;
        if (ASPL == 2) l[j] = (_Float16)(f[j] - (float)hv);
      }
      int off = row * BK + ((ci ^ ((row >> 1) & 3)) << 3);
      *(half8*)(&ldsA[b][0][0][0] + off) = h;
      if (ASPL == 2) *(half8*)(&ldsA[b][1][0][0] + off) = l;
    }
#pragma unroll
    for (int i = 0; i < NCB; ++i) {
      int c = tid + THREADS * i;
      int row = c >> 2, ci = c & 3;
      float f[8] = {rb[i][0].x, rb[i][0].y, rb[i][0].z, rb[i][0].w,
                    rb[i][1].x, rb[i][1].y, rb[i][1].z, rb[i][1].w};
      half8 h, l;
#pragma unroll
      for (int j = 0; j < 8; ++j) {
        _Float16 hv = (_Float16)f[j];
        h[j] = hv;
        if (BSPL == 2) l[j] = (_Float16)(f[j] - (float)hv);
      }
      int off = row * BK + ((ci ^ ((row >> 1) & 3)) << 3);
      *(half8*)(&ldsB[b][0][0][0] + off) = h;
      if (BSPL == 2) *(half8*)(&ldsB[b][1][0][0] + off) = l;
    }
  };

  const int nk = K / BK;
  loadAB(0);
  stageLDS(0);
  if (nk > 1) loadAB(1);
  __syncthreads();

  for (int kt = 0; kt < nk; ++kt) {
    const int cur = kt & 1, nxt = cur ^ 1;
    if (kt + 1 < nk) stageLDS(nxt);
    if (kt + 2 < nk) loadAB(kt + 2);

    half8 af[FM][ASPL];
#pragma unroll
    for (int mi = 0; mi < FM; ++mi)
#pragma unroll
      for (int sa = 0; sa < ASPL; ++sa) {
        int row = wrow * WM + mi * 16 + l15;
        af[mi][sa] = *(const half8*)(&ldsA[cur][sa][0][0] + row * BK + ((g ^ ((row >> 1) & 3)) << 3));
      }
#pragma unroll
    for (int ni = 0; ni < FN; ++ni) {
      half8 bf[BSPL];
#pragma unroll
      for (int sb = 0; sb < BSPL; ++sb) {
        int row = wcol * WN + ni * 16 + l15;
        bf[sb] = *(const half8*)(&ldsB[cur][sb][0][0] + row * BK + ((g ^ ((row >> 1) & 3)) << 3));
      }
#pragma unroll
      for (int mi = 0; mi < FM; ++mi)
#pragma unroll
        for (int sa = 0; sa < ASPL; ++sa)
#pragma unroll
          for (int sb = 0; sb < BSPL; ++sb) {
            if (ASPL == 2 && BSPL == 2 && sa == 1 && sb == 1) continue;
            acc[mi][ni] = __builtin_amdgcn_mfma_f32_16x16x32_f16(af[mi][sa], bf[sb], acc[mi][ni], 0, 0, 0);
          }
    }
    __syncthreads();
  }

#pragma unroll
  for (int mi = 0; mi < FM; ++mi)
#pragma unroll
    for (int ni = 0; ni < FN; ++ni) {
      int col = bcol + wcol * WN + ni * 16 + l15;
      float bv = bias ? bias[col] : 0.f;
#pragma unroll
      for (int j = 0; j < 4; ++j) {
        int r = brow + wrow * WM + mi * 16 + g * 4 + j;
        float v = acc[mi][ni][j] * scale + bv;
        Cg[(size_t)r * ldc + col] = v;
        if constexpr (QF16) {
          if (col < 512) q16out[(size_t)r * 512 + col] = (_Float16)v;
        }
      }
    }
}

// ---------------------------------------------------------------- GEMM f16 x f16 (K3)
// A, B are f16 [rows][K] row-major. C = scale*A@B^T f32; emits softmax stats.
template<int BM,int BN,int THREADS,bool STATS,int MINW>
__global__ __launch_bounds__(THREADS, MINW) void gemm_ff16(
    const _Float16* __restrict__ Ag, int lda,
    const _Float16* __restrict__ Bg, int ldb,
    float* __restrict__ Cg, int ldc,
    int K, float scale,
    float* __restrict__ mxout, float* __restrict__ smout, int ntiles)
{
  constexpr int BK = 32;
  constexpr int WAVES_M = 2, WAVES_N = 2;
  constexpr int WM = BM / WAVES_M, WN = BN / WAVES_N;
  constexpr int FM = WM / 16, FN = WN / 16;
  constexpr int NCA = (BM * 4) / THREADS;   // half8 chunks (thread covers 8 f16)
  constexpr int NCB = (BN * 4) / THREADS;

  __shared__ _Float16 ldsA[2][BM][BK];
  __shared__ _Float16 ldsB[2][BN][BK];

  const int tid  = threadIdx.x;
  const int lane = tid & 63;
  const int wid  = tid >> 6;
  const int wrow = wid >> 1, wcol = wid & 1;
  const int l15  = lane & 15, g = lane >> 4;
  const int brow = blockIdx.y * BM;
  const int bcol = blockIdx.x * BN;

  f32x4 acc[FM][FN];
#pragma unroll
  for (int mi = 0; mi < FM; ++mi)
#pragma unroll
    for (int ni = 0; ni < FN; ++ni)
      acc[mi][ni] = (f32x4){0.f, 0.f, 0.f, 0.f};

  half8 ra[NCA], rb[NCB];

  auto loadAB = [&](int kt) {
    const int k0 = kt * BK;
#pragma unroll
    for (int i = 0; i < NCA; ++i) {
      int c = tid + THREADS * i;
      int row = c >> 2, ci = c & 3;
      ra[i] = *(const half8*)(Ag + (size_t)(brow + row) * lda + k0 + ci * 8);
    }
#pragma unroll
    for (int i = 0; i < NCB; ++i) {
      int c = tid + THREADS * i;
      int row = c >> 2, ci = c & 3;
      rb[i] = *(const half8*)(Bg + (size_t)(bcol + row) * ldb + k0 + ci * 8);
    }
  };

  auto stageLDS = [&](int b) {
#pragma unroll
    for (int i = 0; i < NCA; ++i) {
      int c = tid + THREADS * i;
      int row = c >> 2, ci = c & 3;
      int off = row * BK + ((ci ^ ((row >> 1) & 3)) << 3);
      *(half8*)(&ldsA[b][0][0] + off) = ra[i];
    }
#pragma unroll
    for (int i = 0; i < NCB; ++i) {
      int c = tid + THREADS * i;
      int row = c >> 2, ci = c & 3;
      int off = row * BK + ((ci ^ ((row >> 1) & 3)) << 3);
      *(half8*)(&ldsB[b][0][0] + off) = rb[i];
    }
  };

  const int nk = K / BK;
  loadAB(0);
  stageLDS(0);
  if (nk > 1) loadAB(1);
  __syncthreads();

  for (int kt = 0; kt < nk; ++kt) {
    const int cur = kt & 1, nxt = cur ^ 1;
    if (kt + 1 < nk) stageLDS(nxt);
    if (kt + 2 < nk) loadAB(kt + 2);

    half8 af[FM];
#pragma unroll
    for (int mi = 0; mi < FM; ++mi) {
      int row = wrow * WM + mi * 16 + l15;
      af[mi] = *(const half8*)(&ldsA[cur][0][0] + row * BK + ((g ^ ((row >> 1) & 3)) << 3));
    }
#pragma unroll
    for (int ni = 0; ni < FN; ++ni) {
      int row = wcol * WN + ni * 16 + l15;
      half8 bf = *(const half8*)(&ldsB[cur][0][0] + row * BK + ((g ^ ((row >> 1) & 3)) << 3));
#pragma unroll
      for (int mi = 0; mi < FM; ++mi)
        acc[mi][ni] = __builtin_amdgcn_mfma_f32_16x16x32_f16(af[mi], bf, acc[mi][ni], 0, 0, 0);
    }
    __syncthreads();
  }

#pragma unroll
  for (int mi = 0; mi < FM; ++mi)
#pragma unroll
    for (int ni = 0; ni < FN; ++ni) {
      int col = bcol + wcol * WN + ni * 16 + l15;
#pragma unroll
      for (int j = 0; j < 4; ++j) {
        int r = brow + wrow * WM + mi * 16 + g * 4 + j;
        Cg[(size_t)r * ldc + col] = acc[mi][ni][j] * scale;
      }
    }

  if constexpr (STATS) {
    __shared__ float s_m2[BM][2];
    __shared__ float s_s2[BM][2];
#pragma unroll
    for (int mi = 0; mi < FM; ++mi)
#pragma unroll
      for (int j = 0; j < 4; ++j) {
        float v = -3.4e38f;
#pragma unroll
        for (int ni = 0; ni < FN; ++ni) v = fmaxf(v, acc[mi][ni][j] * scale);
        v = fmaxf(v, __shfl_xor(v, 1)); v = fmaxf(v, __shfl_xor(v, 2));
        v = fmaxf(v, __shfl_xor(v, 4)); v = fmaxf(v, __shfl_xor(v, 8));
        if (l15 == 0) s_m2[wrow * WM + mi * 16 + g * 4 + j][wcol] = v;
      }
    __syncthreads();
#pragma unroll
    for (int mi = 0; mi < FM; ++mi)
#pragma unroll
      for (int j = 0; j < 4; ++j) {
        int r = wrow * WM + mi * 16 + g * 4 + j;
        float mt = fmaxf(s_m2[r][0], s_m2[r][1]);
        float s = 0.f;
#pragma unroll
        for (int ni = 0; ni < FN; ++ni) s += __expf(acc[mi][ni][j] * scale - mt);
        s += __shfl_xor(s, 1); s += __shfl_xor(s, 2);
        s += __shfl_xor(s, 4); s += __shfl_xor(s, 8);
        if (l15 == 0) s_s2[r][wcol] = s;
      }
    __syncthreads();
    if (tid < BM) {
      float mt = fmaxf(s_m2[tid][0], s_m2[tid][1]);
      float st = s_s2[tid][0] + s_s2[tid][1];
      mxout[(size_t)(brow + tid) * ntiles + blockIdx.x] = mt;
      smout[(size_t)(brow + tid) * ntiles + blockIdx.x] = st;
    }
  }
}

// ---------------------------------------------------------------- reduce 4 planes -> f16
// out16 = (sum of 4 partials) - csum[d]  (softmax-invariant shift, shrinks |k| ~2x)
__global__ __launch_bounds__(256) void reduce4_f16(
    const float4* __restrict__ in, _Float16* __restrict__ out16, size_t plane4,
    const float4* __restrict__ csum4)
{
  size_t i = (size_t)blockIdx.x * 256 + threadIdx.x;
  float4 a = in[i], b = in[plane4 + i], c = in[2 * plane4 + i], d = in[3 * plane4 + i];
  float4 s = csum4[i & 127];   // row length 512 f32 = 128 float4
  half4 h;
  h[0] = (_Float16)(a.x + b.x + c.x + d.x - s.x);
  h[1] = (_Float16)(a.y + b.y + c.y + d.y - s.y);
  h[2] = (_Float16)(a.z + b.z + c.z + d.z - s.z);
  h[3] = (_Float16)(a.w + b.w + c.w + d.w - s.w);
  *(half4*)(out16 + i * 4) = h;
}

// ---------------------------------------------------------------- stats combine
__global__ __launch_bounds__(256) void softmax_combine(
    const float* __restrict__ mx, const float* __restrict__ sm,
    float* __restrict__ rowm, float* __restrict__ rowinv)
{
  const int row = blockIdx.x * 4 + (threadIdx.x >> 6);
  const int lane = threadIdx.x & 63;
  float mt = mx[(size_t)row * 64 + lane];
  float m = mt;
#pragma unroll
  for (int off = 32; off; off >>= 1) m = fmaxf(m, __shfl_xor(m, off));
  float s = sm[(size_t)row * 64 + lane] * __expf(mt - m);
#pragma unroll
  for (int off = 32; off; off >>= 1) s += __shfl_xor(s, off);
  if (lane == 0) { rowm[row] = m; rowinv[row] = 1.0f / s; }
}

// ---------------------------------------------------------------- fused attn-write + PV
__global__ __launch_bounds__(512, 4) void pv_fused(
    float* __restrict__ attn,            // [8192][8192] logits in, attention out
    const _Float16* __restrict__ vT16,   // [512][8192] f16
    const float* __restrict__ rowm, const float* __restrict__ rowinv,
    float* __restrict__ vals_p)          // [4][8192][512]
{
  constexpr int BM = 64, BN = 512, BK = 32, NSTEP = 64;  // KC = 2048
  __shared__ _Float16 ldsA[2][BM][BK];   // 8 KB
  __shared__ _Float16 ldsB[2][BN][BK];   // 64 KB
  __shared__ float s_m[BM], s_inv[BM];

  const int tid = threadIdx.x, lane = tid & 63, wid = tid >> 6;
  const int wrow = wid >> 2, wcol = wid & 3;   // 2 x 4 waves
  const int l15 = lane & 15, g = lane >> 4;
  const int kc = blockIdx.x, brow = blockIdx.y * BM;
  const size_t kbase = (size_t)kc * 2048;

  if (tid < BM) { s_m[tid] = rowm[brow + tid]; s_inv[tid] = rowinv[brow + tid]; }

  f32x4 acc[2][8];
#pragma unroll
  for (int mi = 0; mi < 2; ++mi)
#pragma unroll
    for (int ni = 0; ni < 8; ++ni) acc[mi][ni] = (f32x4){0.f, 0.f, 0.f, 0.f};

  const int arow = (tid & 255) >> 2, aci = tid & 3;
  float4 ra[2];
  half8 rbh[4];

  auto loadA = [&](int kt) {
    if (tid < 256) {
      const float4* p = (const float4*)(attn + (size_t)(brow + arow) * 8192 + kbase + kt * BK + aci * 8);
      ra[0] = p[0]; ra[1] = p[1];
    }
  };
  auto loadB = [&](int kt) {
#pragma unroll
    for (int i = 0; i < 4; ++i) {
      int c = tid + 512 * i; int r = c >> 2, ci = c & 3;
      rbh[i] = *(const half8*)(vT16 + (size_t)r * 8192 + kbase + kt * BK + ci * 8);
    }
  };
  auto stage = [&](int kt, int b) {
    if (tid < 256) {
      const float m = s_m[arow], inv = s_inv[arow];
      float f[8] = {ra[0].x, ra[0].y, ra[0].z, ra[0].w, ra[1].x, ra[1].y, ra[1].z, ra[1].w};
      float e[8]; half8 h;
#pragma unroll
      for (int j = 0; j < 8; ++j) {
        e[j] = __expf(f[j] - m) * inv;
        h[j] = (_Float16)e[j];
      }
      float4* w = (float4*)(attn + (size_t)(brow + arow) * 8192 + kbase + kt * BK + aci * 8);
      w[0] = make_float4(e[0], e[1], e[2], e[3]);
      w[1] = make_float4(e[4], e[5], e[6], e[7]);
      int off = arow * BK + ((aci ^ ((arow >> 1) & 3)) << 3);
      *(half8*)(&ldsA[b][0][0] + off) = h;
    }
#pragma unroll
    for (int i = 0; i < 4; ++i) {
      int c = tid + 512 * i; int r = c >> 2, ci = c & 3;
      int off2 = r * BK + ((ci ^ ((r >> 1) & 3)) << 3);
      *(half8*)(&ldsB[b][0][0] + off2) = rbh[i];
    }
  };

  loadA(0); loadB(0);
  __syncthreads();            // s_m / s_inv visible
  stage(0, 0);
  loadA(1); loadB(1);
  __syncthreads();            // buf0 staged

  for (int kt = 0; kt < NSTEP; ++kt) {
    const int cur = kt & 1, nxt = cur ^ 1;
    if (kt + 1 < NSTEP) stage(kt + 1, nxt);
    if (kt + 2 < NSTEP) { loadA(kt + 2); loadB(kt + 2); }
    half8 af[2];
#pragma unroll
    for (int mi = 0; mi < 2; ++mi) {
      int row = wrow * 32 + mi * 16 + l15;
      af[mi] = *(const half8*)(&ldsA[cur][0][0] + row * BK + ((g ^ ((row >> 1) & 3)) << 3));
    }
#pragma unroll
    for (int ni = 0; ni < 8; ++ni) {
      int rn = wcol * 128 + ni * 16 + l15;
      half8 bf = *(const half8*)(&ldsB[cur][0][0] + rn * BK + ((g ^ ((rn >> 1) & 3)) << 3));
#pragma unroll
      for (int mi = 0; mi < 2; ++mi)
        acc[mi][ni] = __builtin_amdgcn_mfma_f32_16x16x32_f16(af[mi], bf, acc[mi][ni], 0, 0, 0);
    }
    __syncthreads();
  }

  const size_t plane = (size_t)8192 * 512;
#pragma unroll
  for (int mi = 0; mi < 2; ++mi)
#pragma unroll
    for (int ni = 0; ni < 8; ++ni) {
      int col = wcol * 128 + ni * 16 + l15;
#pragma unroll
      for (int j = 0; j < 4; ++j) {
        int row = brow + wrow * 32 + mi * 16 + g * 4 + j;
        vals_p[(size_t)kc * plane + (size_t)row * 512 + col] = acc[mi][ni][j];
      }
    }
}

// ---------------------------------------------------------------- launch
extern "C" void kernel_launch(void* const* d_in, const int* in_sizes, int n_in,
                              void* d_out, int out_size, void* d_ws, size_t ws_size,
                              hipStream_t stream)
{
  const float* x    = (const float*)d_in[0];
  const float* Amat = (const float*)d_in[1];
  const float* Wqkv = (const float*)d_in[2];
  const float* bqkv = (const float*)d_in[3];
  const float* Wo   = (const float*)d_in[4];
  const float* bo   = (const float*)d_in[5];

  float* o    = (float*)d_out;                       // [8192,512]
  float* attn = (float*)d_out + (size_t)8192 * 512;  // [8192,8192]

  float* ws = (float*)d_ws;
  float*     vals_p = ws;                         // 16,777,216 floats (4 planes)
  float*     qkv    = ws;                         // 12,582,912 (dead after k0T/vT/q16)
  float*     k0T    = ws + 12582912;              //  4,194,304 (dead after K2/halfcolsum)
  _Float16*  vT16   = (_Float16*)(ws + 16777216); //  2,097,152 float-slots
  float*     WqkvT  = ws + 18874368;              //    786,432
  float*     WoT    = ws + 19660800;              //    262,144
  _Float16*  kbuf16 = (_Float16*)(ws + 19922944); //  2,097,152 float-slots (f16 [8192][512])
  float*     mx     = ws + 24117248;              //    524,288
  float*     sm     = ws + 24641536;              //    524,288
  float*     rowm   = ws + 25165824;              //      8,192
  float*     rowinv = ws + 25174016;              //      8,192
  float*     csum   = ws + 25182208;              //        512 (pad to 1024)
  _Float16*  q16    = (_Float16*)(ws + 25183232); //  2,097,152 float-slots (f16 [8192][512])
  float*     kpart  = attn;                       // d_out attn region pre-K3

  const dim3 b256(256), b512(512);
  const float qk_scale = 0.04419417382415922f;  // 1/sqrt(512)
  const size_t plane = (size_t)8192 * 512;

  transpose_f32<<<dim3(48, 16), b256, 0, stream>>>(Wqkv, 1536, WqkvT, 512);
  transpose_f32<<<dim3(16, 16), b256, 0, stream>>>(Wo, 512, WoT, 512);

  // K1: qkv = x @ Wqkv + bqkv (3-pass) + fused f16 copy of q-third
  gemm_bt<2, 2, 128, 128, 2, 2, 256, 1, false, true, 2>
      <<<dim3(12, 64), b256, 0, stream>>>(
      x, 512, 0, WqkvT, 512, qkv, 1536, 0, bqkv, 512, 1.0f, q16);

  transpose_f32<<<dim3(16, 256), b256, 0, stream>>>(qkv + 512, 1536, k0T, 8192);
  transpose_f32_f16<<<dim3(16, 256), b256, 0, stream>>>(qkv + 1024, 1536, vT16, 8192);
  halfcolsum<<<dim3(512), b256, 0, stream>>>(k0T, csum);

  // K2: k = A @ k0, split-K into 4 chunks, partials in d_out scratch
  gemm_bt<1, 2, 128, 256, 2, 4, 512, 1, true, false, 4>
      <<<dim3(2, 64, 4), b512, 0, stream>>>(
      Amat, 8192, 0, k0T, 8192, kpart, 512, plane, nullptr, 2048, 1.0f, nullptr);

  // kbuf16 = f16(sum of partials - 0.5*colsum(k0))
  reduce4_f16<<<dim3(4096), b256, 0, stream>>>((const float4*)kpart, kbuf16, plane / 4,
                                               (const float4*)csum);

  // K3: logits = (q16 @ kbuf16^T)*scale  (all-f16 staging) + per-tile softmax stats
  gemm_ff16<128, 128, 256, true, 4>
      <<<dim3(64, 64), b256, 0, stream>>>(
      q16, 512, kbuf16, 512, attn, 8192, 512, qk_scale, mx, sm, 64);

  softmax_combine<<<dim3(2048), b256, 0, stream>>>(mx, sm, rowm, rowinv);

  // K5': attention = exp(l-m)/s in place; vals partials (dbuf, 512 blocks)
  pv_fused<<<dim3(4, 128), b512, 0, stream>>>(attn, vT16, rowm, rowinv, vals_p);

  // K6: o = (sum of 4 vals partials) @ Wo + bo
  gemm_bt<1, 1, 128, 128, 2, 2, 256, 4, false, false, 3>
      <<<dim3(4, 64), b256, 0, stream>>>(
      vals_p, 512, plane, WoT, 512, o, 512, 0, bo, 512, 1.0f, nullptr);
}